// Round 2
// baseline (2933.947 us; speedup 1.0000x reference)
//
#include <hip/hip_runtime.h>
#include <hip/hip_fp8.h>
#include <stdint.h>

#define D      512
#define NSTEP  128          // SRC steps == decoder steps (TGT-1)
#define EVOC   50000
#define VTILE  128
#define NBV    ((EVOC + VTILE - 1) / VTILE)   // 391
#define LDK    132          // padded LDS leading dim for GEMM tiles

typedef float v2f __attribute__((ext_vector_type(2)));

// ---- fp8 helpers (storage for recurrent weights; ~6% rel err is fine here) ----
__device__ inline uint8_t f32_to_fp8(float x) {
    __hip_fp8_e4m3 q(x);
    return (uint8_t)q.__x;
}

#if __has_builtin(__builtin_amdgcn_cvt_pk_f32_fp8)
__device__ inline v2f fp8x2_lo(uint32_t w) {
    return __builtin_amdgcn_cvt_pk_f32_fp8((int)w, false);
}
__device__ inline v2f fp8x2_hi(uint32_t w) {
    return __builtin_amdgcn_cvt_pk_f32_fp8((int)w, true);
}
#else
__device__ inline v2f fp8x2_cvt(uint32_t w, int sh) {
    __hip_fp8_e4m3 a, b;
    a.__x = (uint8_t)((w >> sh) & 0xff);
    b.__x = (uint8_t)((w >> (sh + 8)) & 0xff);
    v2f r; r.x = (float)a; r.y = (float)b; return r;
}
__device__ inline v2f fp8x2_lo(uint32_t w) { return fp8x2_cvt(w, 0); }
__device__ inline v2f fp8x2_hi(uint32_t w) { return fp8x2_cvt(w, 16); }
#endif

// ---- K0: convert Whh_e / Whh_d to fp8 bytes (row-major preserved) ----
__global__ void k_convert(const float* __restrict__ We, const float* __restrict__ Wd,
                          uint8_t* __restrict__ e8, uint8_t* __restrict__ d8) {
    int i = blockIdx.x * 256 + threadIdx.x;   // grid covers 512*512
    e8[i] = f32_to_fp8(We[i]);
    d8[i] = f32_to_fp8(Wd[i]);
}

// ---- K1: pre[s][o] = emb[idx[s]] . Wih[o,:] + b[o]   (both enc & dec) ----
__global__ __launch_bounds__(256) void k_pre(
        const int* __restrict__ fnums, const int* __restrict__ enums,
        const float* __restrict__ emb_f, const float* __restrict__ emb_d,
        const float* __restrict__ Wih_e, const float* __restrict__ Wih_d,
        const float* __restrict__ b_e, const float* __restrict__ b_d,
        float* __restrict__ pre_e, float* __restrict__ pre_d) {
    __shared__ float xl[D];
    int bb = blockIdx.x;            // 0..255 : 128 enc + 128 dec
    int kind = bb >> 7, s = bb & 127;
    const float* emb = kind ? emb_d : emb_f;
    int idx          = kind ? enums[s] : fnums[s];
    const float* W   = kind ? Wih_d : Wih_e;
    const float* b   = kind ? b_d : b_e;
    float* pre       = kind ? pre_d : pre_e;
    int t = threadIdx.x;
    xl[t]       = emb[(size_t)idx * D + t];
    xl[t + 256] = emb[(size_t)idx * D + t + 256];
    __syncthreads();
    for (int rep = 0; rep < 2; rep++) {
        int o = t + rep * 256;
        float acc = b[o];
        const float4* Wr = (const float4*)(W + (size_t)o * D);
        #pragma unroll 8
        for (int k4 = 0; k4 < D / 4; k4++) {
            float4 w = Wr[k4];
            acc += w.x * xl[4*k4] + w.y * xl[4*k4+1] + w.z * xl[4*k4+2] + w.w * xl[4*k4+3];
        }
        pre[(size_t)s * D + o] = acc;
    }
}

// ---- K2: the two sequential scans. One block each; Whh (fp8) lives in VGPRs. ----
__global__ __launch_bounds__(512) void k_scan(
        const uint8_t* __restrict__ w8_e, const uint8_t* __restrict__ w8_d,
        const float* __restrict__ pre_e, const float* __restrict__ pre_d,
        const float* __restrict__ h0_e, const float* __restrict__ h0_d,
        float* __restrict__ fencs, float* __restrict__ h2s) {
    __shared__ float h[2][D];
    int t = threadIdx.x;                         // t == output row
    const uint8_t* w8 = blockIdx.x ? w8_d : w8_e;
    const float* pre  = blockIdx.x ? pre_d : pre_e;
    const float* h0   = blockIdx.x ? h0_d : h0_e;
    float* hs         = blockIdx.x ? h2s : fencs;

    // preload row of Whh: 512 fp8 = 128 u32 in registers
    uint32_t w[128];
    const uint32_t* wrow = (const uint32_t*)(w8 + (size_t)t * D);
    #pragma unroll
    for (int q = 0; q < 128; q++) w[q] = wrow[q];

    h[0][t] = h0[t];
    __syncthreads();

    int p = 0;
    for (int step = 0; step < NSTEP; step++) {
        float a0 = pre[(size_t)step * D + t];
        float a1 = 0.f, a2 = 0.f, a3 = 0.f;
        const float4* hv = (const float4*)h[p];
        #pragma unroll
        for (int q = 0; q < 128; q++) {
            float4 hx = hv[q];                  // broadcast LDS read
            uint32_t wq = w[q];
            v2f lo = fp8x2_lo(wq);
            v2f hi = fp8x2_hi(wq);
            a0 += lo.x * hx.x;
            a1 += lo.y * hx.y;
            a2 += hi.x * hx.z;
            a3 += hi.y * hx.w;
        }
        float h2 = tanhf((a0 + a1) + (a2 + a3));
        hs[(size_t)step * D + t] = h2;
        h[p ^ 1][t] = h2;
        p ^= 1;
        __syncthreads();
    }
}

// ---- K3: per decoder step: attention + m = tanh([c,h2] @ Wm^T + bm) ----
__global__ __launch_bounds__(256) void k_att(
        const float* __restrict__ fencs, const float* __restrict__ h2s,
        const float* __restrict__ Wm, const float* __restrict__ bm,
        float* __restrict__ m_all) {
    __shared__ float h2l[D], cl[D], sc[NSTEP], red[64];
    int s = blockIdx.x, t = threadIdx.x;
    h2l[t]       = h2s[(size_t)s * D + t];
    h2l[t + 256] = h2s[(size_t)s * D + t + 256];
    __syncthreads();

    if (t < NSTEP) {                    // scores[j] = fencs[j] . h2
        float acc = 0.f;
        const float4* fr = (const float4*)(fencs + (size_t)t * D);
        const float4* hr = (const float4*)h2l;
        #pragma unroll 8
        for (int k4 = 0; k4 < D / 4; k4++) {
            float4 f = fr[k4], hh = hr[k4];
            acc += f.x*hh.x + f.y*hh.y + f.z*hh.z + f.w*hh.w;
        }
        sc[t] = acc;
    }
    __syncthreads();
    if (t < 64) {
        float m = fmaxf(sc[t], sc[t + 64]);
        for (int off = 32; off; off >>= 1) m = fmaxf(m, __shfl_xor(m, off));
        if (t == 0) red[0] = m;
    }
    __syncthreads();
    float mx = red[0];
    __syncthreads();
    if (t < NSTEP) sc[t] = expf(sc[t] - mx);
    __syncthreads();
    if (t < 64) {
        float v = sc[t] + sc[t + 64];
        for (int off = 32; off; off >>= 1) v += __shfl_xor(v, off);
        if (t == 0) red[0] = v;
    }
    __syncthreads();
    float inv = 1.0f / red[0];

    for (int rep = 0; rep < 2; rep++) {         // c[k] = sum_j alpha[j]*fencs[j][k]
        int k = t + rep * 256;
        float acc = 0.f;
        for (int j = 0; j < NSTEP; j++) acc += sc[j] * fencs[(size_t)j * D + k];
        cl[k] = acc * inv;
    }
    __syncthreads();

    for (int rep = 0; rep < 2; rep++) {         // m[o] = tanh(Wm[o,:512].c + Wm[o,512:].h2 + bm)
        int o = t + rep * 256;
        float acc = bm[o];
        const float4* wr = (const float4*)(Wm + (size_t)o * 2 * D);
        const float4* cr = (const float4*)cl;
        const float4* hr = (const float4*)h2l;
        #pragma unroll 4
        for (int k4 = 0; k4 < D / 4; k4++) {
            float4 w = wr[k4], c = cr[k4];
            acc += w.x*c.x + w.y*c.y + w.z*c.z + w.w*c.w;
        }
        #pragma unroll 4
        for (int k4 = 0; k4 < D / 4; k4++) {
            float4 w = wr[D/4 + k4], hh = hr[k4];
            acc += w.x*hh.x + w.y*hh.y + w.z*hh.z + w.w*hh.w;
        }
        m_all[(size_t)s * D + o] = tanhf(acc);
    }
}

// ---- K4: logits tile GEMM (128 steps x 128 vocab, K=512) + fused row max/sumexp ----
__global__ __launch_bounds__(256) void k_logits(
        const float* __restrict__ m_all, const float* __restrict__ Wo,
        const float* __restrict__ bo, const int* __restrict__ enums,
        float* __restrict__ pmax, float* __restrict__ psum, float* __restrict__ pick) {
    __shared__ float a_s[32 * LDK], b_s[32 * LDK];
    int b = blockIdx.x, t = threadIdx.x;
    int v0 = b * VTILE;
    int ti = t >> 4, tj = t & 15;
    int lk = t & 31, lr = t >> 5;
    float acc[8][8] = {};

    for (int kc = 0; kc < 16; kc++) {
        int k0 = kc * 32;
        #pragma unroll
        for (int ps = 0; ps < 16; ps++) {
            int row = ps * 8 + lr;
            a_s[lk * LDK + row] = m_all[(size_t)row * D + k0 + lk];
            int v = v0 + row;
            b_s[lk * LDK + row] = (v < EVOC) ? Wo[(size_t)v * D + k0 + lk] : 0.f;
        }
        __syncthreads();
        #pragma unroll
        for (int k = 0; k < 32; k++) {
            const float4* ar = (const float4*)(a_s + k * LDK + ti * 8);
            float4 av0 = ar[0], av1 = ar[1];
            const float4* br = (const float4*)(b_s + k * LDK + tj * 8);
            float4 bv0 = br[0], bv1 = br[1];
            float av[8] = {av0.x, av0.y, av0.z, av0.w, av1.x, av1.y, av1.z, av1.w};
            float bv[8] = {bv0.x, bv0.y, bv0.z, bv0.w, bv1.x, bv1.y, bv1.z, bv1.w};
            #pragma unroll
            for (int i = 0; i < 8; i++)
                #pragma unroll
                for (int j = 0; j < 8; j++)
                    acc[i][j] += av[i] * bv[j];
        }
        __syncthreads();
    }

    #pragma unroll
    for (int i = 0; i < 8; i++) {
        int s = ti * 8 + i;
        float l[8];
        float mx = -1e30f;
        #pragma unroll
        for (int j = 0; j < 8; j++) {
            int v = v0 + tj * 8 + j;
            l[j] = (v < EVOC) ? acc[i][j] + bo[v] : -1e30f;
            mx = fmaxf(mx, l[j]);
        }
        for (int m = 1; m < 16; m <<= 1) mx = fmaxf(mx, __shfl_xor(mx, m));
        float sm = 0.f;
        #pragma unroll
        for (int j = 0; j < 8; j++) {
            int v = v0 + tj * 8 + j;
            if (v < EVOC) sm += expf(l[j] - mx);
        }
        for (int m = 1; m < 16; m <<= 1) sm += __shfl_xor(sm, m);
        if (tj == 0) { pmax[b * NSTEP + s] = mx; psum[b * NSTEP + s] = sm; }
        int tgt = enums[s + 1];
        if (tgt >= v0 && tgt < v0 + VTILE) {
            int jj = tgt - v0;
            if ((jj >> 3) == tj) pick[s] = l[jj & 7];
        }
    }
}

// ---- K5: combine partial logsumexps, pick target logprobs, sum ----
__global__ void k_final(const float* __restrict__ pmax, const float* __restrict__ psum,
                        const float* __restrict__ pick, float* __restrict__ out) {
    __shared__ float red[NSTEP];
    int t = threadIdx.x;     // 128 threads, one per decoder step
    float M = -1e30f;
    for (int b = 0; b < NBV; b++) M = fmaxf(M, pmax[b * NSTEP + t]);
    float S = 0.f;
    for (int b = 0; b < NBV; b++) S += psum[b * NSTEP + t] * expf(pmax[b * NSTEP + t] - M);
    red[t] = pick[t] - (M + logf(S));
    __syncthreads();
    for (int off = 64; off > 0; off >>= 1) {
        if (t < off) red[t] += red[t + off];
        __syncthreads();
    }
    if (t == 0) out[0] = red[0];
}

extern "C" void kernel_launch(void* const* d_in, const int* in_sizes, int n_in,
                              void* d_out, int out_size, void* d_ws, size_t ws_size,
                              hipStream_t stream) {
    const int*   fnums = (const int*)  d_in[0];
    const int*   enums = (const int*)  d_in[1];
    const float* emb_f = (const float*)d_in[2];
    const float* Wih_e = (const float*)d_in[3];
    const float* Whh_e = (const float*)d_in[4];
    const float* b_e   = (const float*)d_in[5];
    const float* h0_e  = (const float*)d_in[6];
    const float* emb_d = (const float*)d_in[7];
    const float* Wih_d = (const float*)d_in[8];
    const float* Whh_d = (const float*)d_in[9];
    const float* b_d   = (const float*)d_in[10];
    const float* h0_d  = (const float*)d_in[11];
    const float* Wm    = (const float*)d_in[12];
    const float* bm    = (const float*)d_in[13];
    const float* Wo    = (const float*)d_in[14];
    const float* bo    = (const float*)d_in[15];

    float* ws = (float*)d_ws;
    float* pre_e = ws;                 // 128*512
    float* pre_d = ws + 65536;
    float* fencs = ws + 131072;
    float* h2s   = ws + 196608;
    float* m_all = ws + 262144;
    float* pmax  = ws + 327680;        // 391*128
    float* psum  = ws + 377728;
    float* pick  = ws + 427776;        // 128
    uint8_t* w8e = (uint8_t*)(ws + 427904);  // 256 KB
    uint8_t* w8d = w8e + D * D;              // 256 KB

    k_convert<<<dim3(D * D / 256), dim3(256), 0, stream>>>(Whh_e, Whh_d, w8e, w8d);
    k_pre<<<dim3(256), dim3(256), 0, stream>>>(fnums, enums, emb_f, emb_d,
                                               Wih_e, Wih_d, b_e, b_d, pre_e, pre_d);
    k_scan<<<dim3(2), dim3(512), 0, stream>>>(w8e, w8d, pre_e, pre_d, h0_e, h0_d, fencs, h2s);
    k_att<<<dim3(NSTEP), dim3(256), 0, stream>>>(fencs, h2s, Wm, bm, m_all);
    k_logits<<<dim3(NBV), dim3(256), 0, stream>>>(m_all, Wo, bo, enums, pmax, psum, pick);
    k_final<<<dim3(1), dim3(NSTEP), 0, stream>>>(pmax, psum, pick, (float*)d_out);
}

// Round 3
// 2929.845 us; speedup vs baseline: 1.0014x; 1.0014x over previous
//
#include <hip/hip_runtime.h>
#include <hip/hip_fp8.h>
#include <stdint.h>

#define D      512
#define NSTEP  128          // SRC steps == decoder steps (TGT-1)
#define EVOC   50000
#define VTILE  128
#define NBV    ((EVOC + VTILE - 1) / VTILE)   // 391
#define LDK    132          // padded LDS leading dim for GEMM tiles

typedef float v2f __attribute__((ext_vector_type(2)));

// ---- fp8 helpers (storage for recurrent weights; ~6% rel err is fine here) ----
__device__ inline uint8_t f32_to_fp8(float x) {
    __hip_fp8_e4m3 q(x);
    return (uint8_t)q.__x;
}

#if __has_builtin(__builtin_amdgcn_cvt_pk_f32_fp8)
__device__ inline v2f fp8x2_lo(uint32_t w) {
    return __builtin_amdgcn_cvt_pk_f32_fp8((int)w, false);
}
__device__ inline v2f fp8x2_hi(uint32_t w) {
    return __builtin_amdgcn_cvt_pk_f32_fp8((int)w, true);
}
#else
__device__ inline v2f fp8x2_cvt(uint32_t w, int sh) {
    __hip_fp8_e4m3 a, b;
    a.__x = (uint8_t)((w >> sh) & 0xff);
    b.__x = (uint8_t)((w >> (sh + 8)) & 0xff);
    v2f r; r.x = (float)a; r.y = (float)b; return r;
}
__device__ inline v2f fp8x2_lo(uint32_t w) { return fp8x2_cvt(w, 0); }
__device__ inline v2f fp8x2_hi(uint32_t w) { return fp8x2_cvt(w, 16); }
#endif

// ---- K0: convert Whh_e / Whh_d to fp8 bytes (row-major preserved) ----
__global__ void k_convert(const float* __restrict__ We, const float* __restrict__ Wd,
                          uint8_t* __restrict__ e8, uint8_t* __restrict__ d8) {
    int i = blockIdx.x * 256 + threadIdx.x;   // grid covers 512*512
    e8[i] = f32_to_fp8(We[i]);
    d8[i] = f32_to_fp8(Wd[i]);
}

// ---- K1: pre[s][o] = emb[idx[s]] . Wih[o,:] + b[o]   (both enc & dec) ----
__global__ __launch_bounds__(256) void k_pre(
        const int* __restrict__ fnums, const int* __restrict__ enums,
        const float* __restrict__ emb_f, const float* __restrict__ emb_d,
        const float* __restrict__ Wih_e, const float* __restrict__ Wih_d,
        const float* __restrict__ b_e, const float* __restrict__ b_d,
        float* __restrict__ pre_e, float* __restrict__ pre_d) {
    __shared__ float xl[D];
    int bb = blockIdx.x;            // 0..255 : 128 enc + 128 dec
    int kind = bb >> 7, s = bb & 127;
    const float* emb = kind ? emb_d : emb_f;
    int idx          = kind ? enums[s] : fnums[s];
    const float* W   = kind ? Wih_d : Wih_e;
    const float* b   = kind ? b_d : b_e;
    float* pre       = kind ? pre_d : pre_e;
    int t = threadIdx.x;
    xl[t]       = emb[(size_t)idx * D + t];
    xl[t + 256] = emb[(size_t)idx * D + t + 256];
    __syncthreads();
    for (int rep = 0; rep < 2; rep++) {
        int o = t + rep * 256;
        float acc = b[o];
        const float4* Wr = (const float4*)(W + (size_t)o * D);
        #pragma unroll 8
        for (int k4 = 0; k4 < D / 4; k4++) {
            float4 w = Wr[k4];
            acc += w.x * xl[4*k4] + w.y * xl[4*k4+1] + w.z * xl[4*k4+2] + w.w * xl[4*k4+3];
        }
        pre[(size_t)s * D + o] = acc;
    }
}

// ---- K2: the two sequential scans. One block each; Whh (fp8) lives in VGPRs. ----
// __launch_bounds__(512, 2): 8 waves/block = 2 waves/SIMD -> 256-VGPR budget so
// the 128-u32 weight row stays in registers (at the default 128-VGPR cap it
// spilled to scratch: 19us/step, 2.4ms total).
__global__ __launch_bounds__(512, 2) void k_scan(
        const uint8_t* __restrict__ w8_e, const uint8_t* __restrict__ w8_d,
        const float* __restrict__ pre_e, const float* __restrict__ pre_d,
        const float* __restrict__ h0_e, const float* __restrict__ h0_d,
        float* __restrict__ fencs, float* __restrict__ h2s) {
    __shared__ float h[2][D];
    int t = threadIdx.x;                         // t == output row
    const uint8_t* w8 = blockIdx.x ? w8_d : w8_e;
    const float* pre  = blockIdx.x ? pre_d : pre_e;
    const float* h0   = blockIdx.x ? h0_d : h0_e;
    float* hs         = blockIdx.x ? h2s : fencs;

    // preload row of Whh: 512 fp8 = 128 u32 in registers
    uint32_t w[128];
    const uint32_t* wrow = (const uint32_t*)(w8 + (size_t)t * D);
    #pragma unroll
    for (int q = 0; q < 128; q++) w[q] = wrow[q];

    h[0][t] = h0[t];
    __syncthreads();

    int p = 0;
    for (int step = 0; step < NSTEP; step++) {
        float a0 = pre[(size_t)step * D + t];
        float a1 = 0.f, a2 = 0.f, a3 = 0.f;
        const float4* hv = (const float4*)h[p];
        #pragma unroll
        for (int q = 0; q < 128; q++) {
            float4 hx = hv[q];                  // broadcast LDS read
            uint32_t wq = w[q];
            v2f lo = fp8x2_lo(wq);
            v2f hi = fp8x2_hi(wq);
            a0 += lo.x * hx.x;
            a1 += lo.y * hx.y;
            a2 += hi.x * hx.z;
            a3 += hi.y * hx.w;
        }
        float h2 = tanhf((a0 + a1) + (a2 + a3));
        hs[(size_t)step * D + t] = h2;
        h[p ^ 1][t] = h2;
        p ^= 1;
        __syncthreads();
    }
}

// ---- K3: per decoder step: attention + m = tanh([c,h2] @ Wm^T + bm) ----
__global__ __launch_bounds__(256) void k_att(
        const float* __restrict__ fencs, const float* __restrict__ h2s,
        const float* __restrict__ Wm, const float* __restrict__ bm,
        float* __restrict__ m_all) {
    __shared__ float h2l[D], cl[D], sc[NSTEP], red[64];
    int s = blockIdx.x, t = threadIdx.x;
    h2l[t]       = h2s[(size_t)s * D + t];
    h2l[t + 256] = h2s[(size_t)s * D + t + 256];
    __syncthreads();

    if (t < NSTEP) {                    // scores[j] = fencs[j] . h2
        float acc = 0.f;
        const float4* fr = (const float4*)(fencs + (size_t)t * D);
        const float4* hr = (const float4*)h2l;
        #pragma unroll 8
        for (int k4 = 0; k4 < D / 4; k4++) {
            float4 f = fr[k4], hh = hr[k4];
            acc += f.x*hh.x + f.y*hh.y + f.z*hh.z + f.w*hh.w;
        }
        sc[t] = acc;
    }
    __syncthreads();
    if (t < 64) {
        float m = fmaxf(sc[t], sc[t + 64]);
        for (int off = 32; off; off >>= 1) m = fmaxf(m, __shfl_xor(m, off));
        if (t == 0) red[0] = m;
    }
    __syncthreads();
    float mx = red[0];
    __syncthreads();
    if (t < NSTEP) sc[t] = expf(sc[t] - mx);
    __syncthreads();
    if (t < 64) {
        float v = sc[t] + sc[t + 64];
        for (int off = 32; off; off >>= 1) v += __shfl_xor(v, off);
        if (t == 0) red[0] = v;
    }
    __syncthreads();
    float inv = 1.0f / red[0];

    for (int rep = 0; rep < 2; rep++) {         // c[k] = sum_j alpha[j]*fencs[j][k]
        int k = t + rep * 256;
        float acc = 0.f;
        for (int j = 0; j < NSTEP; j++) acc += sc[j] * fencs[(size_t)j * D + k];
        cl[k] = acc * inv;
    }
    __syncthreads();

    for (int rep = 0; rep < 2; rep++) {         // m[o] = tanh(Wm[o,:512].c + Wm[o,512:].h2 + bm)
        int o = t + rep * 256;
        float acc = bm[o];
        const float4* wr = (const float4*)(Wm + (size_t)o * 2 * D);
        const float4* cr = (const float4*)cl;
        const float4* hr = (const float4*)h2l;
        #pragma unroll 4
        for (int k4 = 0; k4 < D / 4; k4++) {
            float4 w = wr[k4], c = cr[k4];
            acc += w.x*c.x + w.y*c.y + w.z*c.z + w.w*c.w;
        }
        #pragma unroll 4
        for (int k4 = 0; k4 < D / 4; k4++) {
            float4 w = wr[D/4 + k4], hh = hr[k4];
            acc += w.x*hh.x + w.y*hh.y + w.z*hh.z + w.w*hh.w;
        }
        m_all[(size_t)s * D + o] = tanhf(acc);
    }
}

// ---- K4: logits tile GEMM (128 steps x 128 vocab, K=512) + fused row max/sumexp ----
__global__ __launch_bounds__(256) void k_logits(
        const float* __restrict__ m_all, const float* __restrict__ Wo,
        const float* __restrict__ bo, const int* __restrict__ enums,
        float* __restrict__ pmax, float* __restrict__ psum, float* __restrict__ pick) {
    __shared__ float a_s[32 * LDK], b_s[32 * LDK];
    int b = blockIdx.x, t = threadIdx.x;
    int v0 = b * VTILE;
    int ti = t >> 4, tj = t & 15;
    int lk = t & 31, lr = t >> 5;
    float acc[8][8] = {};

    for (int kc = 0; kc < 16; kc++) {
        int k0 = kc * 32;
        #pragma unroll
        for (int ps = 0; ps < 16; ps++) {
            int row = ps * 8 + lr;
            a_s[lk * LDK + row] = m_all[(size_t)row * D + k0 + lk];
            int v = v0 + row;
            b_s[lk * LDK + row] = (v < EVOC) ? Wo[(size_t)v * D + k0 + lk] : 0.f;
        }
        __syncthreads();
        #pragma unroll
        for (int k = 0; k < 32; k++) {
            const float4* ar = (const float4*)(a_s + k * LDK + ti * 8);
            float4 av0 = ar[0], av1 = ar[1];
            const float4* br = (const float4*)(b_s + k * LDK + tj * 8);
            float4 bv0 = br[0], bv1 = br[1];
            float av[8] = {av0.x, av0.y, av0.z, av0.w, av1.x, av1.y, av1.z, av1.w};
            float bv[8] = {bv0.x, bv0.y, bv0.z, bv0.w, bv1.x, bv1.y, bv1.z, bv1.w};
            #pragma unroll
            for (int i = 0; i < 8; i++)
                #pragma unroll
                for (int j = 0; j < 8; j++)
                    acc[i][j] += av[i] * bv[j];
        }
        __syncthreads();
    }

    #pragma unroll
    for (int i = 0; i < 8; i++) {
        int s = ti * 8 + i;
        float l[8];
        float mx = -1e30f;
        #pragma unroll
        for (int j = 0; j < 8; j++) {
            int v = v0 + tj * 8 + j;
            l[j] = (v < EVOC) ? acc[i][j] + bo[v] : -1e30f;
            mx = fmaxf(mx, l[j]);
        }
        for (int m = 1; m < 16; m <<= 1) mx = fmaxf(mx, __shfl_xor(mx, m));
        float sm = 0.f;
        #pragma unroll
        for (int j = 0; j < 8; j++) {
            int v = v0 + tj * 8 + j;
            if (v < EVOC) sm += expf(l[j] - mx);
        }
        for (int m = 1; m < 16; m <<= 1) sm += __shfl_xor(sm, m);
        if (tj == 0) { pmax[b * NSTEP + s] = mx; psum[b * NSTEP + s] = sm; }
        int tgt = enums[s + 1];
        if (tgt >= v0 && tgt < v0 + VTILE) {
            int jj = tgt - v0;
            if ((jj >> 3) == tj) pick[s] = l[jj & 7];
        }
    }
}

// ---- K5: combine partial logsumexps, pick target logprobs, sum ----
__global__ void k_final(const float* __restrict__ pmax, const float* __restrict__ psum,
                        const float* __restrict__ pick, float* __restrict__ out) {
    __shared__ float red[NSTEP];
    int t = threadIdx.x;     // 128 threads, one per decoder step
    float M = -1e30f;
    for (int b = 0; b < NBV; b++) M = fmaxf(M, pmax[b * NSTEP + t]);
    float S = 0.f;
    for (int b = 0; b < NBV; b++) S += psum[b * NSTEP + t] * expf(pmax[b * NSTEP + t] - M);
    red[t] = pick[t] - (M + logf(S));
    __syncthreads();
    for (int off = 64; off > 0; off >>= 1) {
        if (t < off) red[t] += red[t + off];
        __syncthreads();
    }
    if (t == 0) out[0] = red[0];
}

extern "C" void kernel_launch(void* const* d_in, const int* in_sizes, int n_in,
                              void* d_out, int out_size, void* d_ws, size_t ws_size,
                              hipStream_t stream) {
    const int*   fnums = (const int*)  d_in[0];
    const int*   enums = (const int*)  d_in[1];
    const float* emb_f = (const float*)d_in[2];
    const float* Wih_e = (const float*)d_in[3];
    const float* Whh_e = (const float*)d_in[4];
    const float* b_e   = (const float*)d_in[5];
    const float* h0_e  = (const float*)d_in[6];
    const float* emb_d = (const float*)d_in[7];
    const float* Wih_d = (const float*)d_in[8];
    const float* Whh_d = (const float*)d_in[9];
    const float* b_d   = (const float*)d_in[10];
    const float* h0_d  = (const float*)d_in[11];
    const float* Wm    = (const float*)d_in[12];
    const float* bm    = (const float*)d_in[13];
    const float* Wo    = (const float*)d_in[14];
    const float* bo    = (const float*)d_in[15];

    float* ws = (float*)d_ws;
    float* pre_e = ws;                 // 128*512
    float* pre_d = ws + 65536;
    float* fencs = ws + 131072;
    float* h2s   = ws + 196608;
    float* m_all = ws + 262144;
    float* pmax  = ws + 327680;        // 391*128
    float* psum  = ws + 377728;
    float* pick  = ws + 427776;        // 128
    uint8_t* w8e = (uint8_t*)(ws + 427904);  // 256 KB
    uint8_t* w8d = w8e + D * D;              // 256 KB

    k_convert<<<dim3(D * D / 256), dim3(256), 0, stream>>>(Whh_e, Whh_d, w8e, w8d);
    k_pre<<<dim3(256), dim3(256), 0, stream>>>(fnums, enums, emb_f, emb_d,
                                               Wih_e, Wih_d, b_e, b_d, pre_e, pre_d);
    k_scan<<<dim3(2), dim3(512), 0, stream>>>(w8e, w8d, pre_e, pre_d, h0_e, h0_d, fencs, h2s);
    k_att<<<dim3(NSTEP), dim3(256), 0, stream>>>(fencs, h2s, Wm, bm, m_all);
    k_logits<<<dim3(NBV), dim3(256), 0, stream>>>(m_all, Wo, bo, enums, pmax, psum, pick);
    k_final<<<dim3(1), dim3(NSTEP), 0, stream>>>(pmax, psum, pick, (float*)d_out);
}

// Round 4
// 708.746 us; speedup vs baseline: 4.1396x; 4.1338x over previous
//
#include <hip/hip_runtime.h>
#include <stdint.h>

#define D      512
#define NSTEP  128          // SRC steps == decoder steps (TGT-1)
#define EVOC   50000
#define VTILE  128
#define NBV    ((EVOC + VTILE - 1) / VTILE)   // 391
#define LDK    132          // padded LDS leading dim for GEMM tiles

// ---- int8 dot4 (v_dot4_i32_i8) ----
__device__ inline int sdot4(int a, int b, int c) {
#if __has_builtin(__builtin_amdgcn_sdot4)
    return __builtin_amdgcn_sdot4(a, b, c, false);
#else
    int r = c;
    r += (int)(int8_t)(a)       * (int)(int8_t)(b);
    r += (int)(int8_t)(a >> 8)  * (int)(int8_t)(b >> 8);
    r += (int)(int8_t)(a >> 16) * (int)(int8_t)(b >> 16);
    r += (int)(int8_t)(a >> 24) * (int)(int8_t)(b >> 24);
    return r;
#endif
}

__device__ inline uint32_t pack4(float a, float b, float c, float d, float inv) {
    return  ((uint32_t)(uint8_t)(int8_t)__float2int_rn(a * inv)) |
            ((uint32_t)(uint8_t)(int8_t)__float2int_rn(b * inv) << 8) |
            ((uint32_t)(uint8_t)(int8_t)__float2int_rn(c * inv) << 16) |
            ((uint32_t)(uint8_t)(int8_t)__float2int_rn(d * inv) << 24);
}

// ---- K0: per-row symmetric int8 quantization of Whh_e / Whh_d ----
// grid 1024 x 64: block = one wave = one row of one matrix
__global__ __launch_bounds__(64) void k_quant(
        const float* __restrict__ We, const float* __restrict__ Wd,
        int8_t* __restrict__ q8, float* __restrict__ qsc) {
    int bid = blockIdx.x;                 // 0..1023
    int which = bid >> 9, row = bid & 511;
    const float* W = which ? Wd : We;
    int lane = threadIdx.x;
    const float* src = W + (size_t)row * D + lane * 8;
    float4 v0 = ((const float4*)src)[0];
    float4 v1 = ((const float4*)src)[1];
    float m = fmaxf(fmaxf(fmaxf(fabsf(v0.x), fabsf(v0.y)), fmaxf(fabsf(v0.z), fabsf(v0.w))),
                    fmaxf(fmaxf(fabsf(v1.x), fabsf(v1.y)), fmaxf(fabsf(v1.z), fabsf(v1.w))));
    for (int off = 32; off; off >>= 1) m = fmaxf(m, __shfl_xor(m, off));
    float inv = (m > 0.f) ? 127.f / m : 0.f;
    uint32_t lo = pack4(v0.x, v0.y, v0.z, v0.w, inv);
    uint32_t hi = pack4(v1.x, v1.y, v1.z, v1.w, inv);
    uint2* dst = (uint2*)(q8 + (size_t)which * D * D + (size_t)row * D);
    dst[lane] = make_uint2(lo, hi);
    if (lane == 0) qsc[which * D + row] = m / 127.f;
}

// ---- K1: pre[s][o] = emb[idx[s]] . Wih[o,:] + b[o]   (both enc & dec) ----
__global__ __launch_bounds__(256) void k_pre(
        const int* __restrict__ fnums, const int* __restrict__ enums,
        const float* __restrict__ emb_f, const float* __restrict__ emb_d,
        const float* __restrict__ Wih_e, const float* __restrict__ Wih_d,
        const float* __restrict__ b_e, const float* __restrict__ b_d,
        float* __restrict__ pre_e, float* __restrict__ pre_d) {
    __shared__ float xl[D];
    int bb = blockIdx.x;            // 0..255 : 128 enc + 128 dec
    int kind = bb >> 7, s = bb & 127;
    const float* emb = kind ? emb_d : emb_f;
    int idx          = kind ? enums[s] : fnums[s];
    const float* W   = kind ? Wih_d : Wih_e;
    const float* b   = kind ? b_d : b_e;
    float* pre       = kind ? pre_d : pre_e;
    int t = threadIdx.x;
    xl[t]       = emb[(size_t)idx * D + t];
    xl[t + 256] = emb[(size_t)idx * D + t + 256];
    __syncthreads();
    for (int rep = 0; rep < 2; rep++) {
        int o = t + rep * 256;
        float acc = b[o];
        const float4* Wr = (const float4*)(W + (size_t)o * D);
        #pragma unroll 8
        for (int k4 = 0; k4 < D / 4; k4++) {
            float4 w = Wr[k4];
            acc += w.x * xl[4*k4] + w.y * xl[4*k4+1] + w.z * xl[4*k4+2] + w.w * xl[4*k4+3];
        }
        pre[(size_t)s * D + o] = acc;
    }
}

// ---- K2: the two sequential scans, int8 x dot4. ----
// 1024 threads: 2 lanes per output row (row = t>>1, half = t&1). Each lane
// keeps 64 u32 (256 int8 weights) in VGPRs -> ~95 regs, fits the mandatory
// 128-VGPR cap of a 16-wave block with no spill (the 128-u32/lane variant
// spilled and ran 19us/step re-reading L2).
__global__ __launch_bounds__(1024) void k_scan(
        const int8_t* __restrict__ q8, const float* __restrict__ qsc,
        const float* __restrict__ pre_e, const float* __restrict__ pre_d,
        const float* __restrict__ h0_e, const float* __restrict__ h0_d,
        float* __restrict__ fencs, float* __restrict__ h2s) {
    __shared__ int8_t hq[2][D];
    int t = threadIdx.x;
    int r = t >> 1, hf = t & 1;
    int which = blockIdx.x;
    const int8_t* w8 = q8 + (size_t)which * D * D;
    const float*  pre = which ? pre_d : pre_e;
    const float*  h0  = which ? h0_d : h0_e;
    float*        hs  = which ? h2s : fencs;
    float sw = qsc[which * D + r] * (1.f / 127.f);

    uint32_t w[64];
    const uint4* wr = (const uint4*)(w8 + (size_t)r * D + hf * 256);
    #pragma unroll
    for (int i = 0; i < 16; i++) {
        uint4 v = wr[i];
        w[4*i] = v.x; w[4*i+1] = v.y; w[4*i+2] = v.z; w[4*i+3] = v.w;
    }

    if (hf == 0) {
        float h0v = fminf(fmaxf(h0[r], -0.999f), 0.999f);
        hq[0][r] = (int8_t)__float2int_rn(h0v * 127.f);
    }
    __syncthreads();

    int p = 0;
    for (int step = 0; step < NSTEP; step++) {
        float prev = pre[(size_t)step * D + r];    // same addr for lane pair (broadcast)
        const uint4* hv = (const uint4*)(&hq[p][hf * 256]);
        int a0 = 0, a1 = 0, a2 = 0, a3 = 0;
        #pragma unroll
        for (int i = 0; i < 16; i++) {
            uint4 hx = hv[i];
            a0 = sdot4((int)w[4*i+0], (int)hx.x, a0);
            a1 = sdot4((int)w[4*i+1], (int)hx.y, a1);
            a2 = sdot4((int)w[4*i+2], (int)hx.z, a2);
            a3 = sdot4((int)w[4*i+3], (int)hx.w, a3);
        }
        int acc = (a0 + a1) + (a2 + a3);
        acc += __shfl_xor(acc, 1);                 // combine the two half-rows
        if (hf == 0) {
            float h2 = tanhf(prev + (float)acc * sw);
            hs[(size_t)step * D + r] = h2;
            hq[p ^ 1][r] = (int8_t)__float2int_rn(h2 * 127.f);
        }
        p ^= 1;
        __syncthreads();
    }
}

// ---- K3: per decoder step: attention + m = tanh([c,h2] @ Wm^T + bm) ----
__global__ __launch_bounds__(256) void k_att(
        const float* __restrict__ fencs, const float* __restrict__ h2s,
        const float* __restrict__ Wm, const float* __restrict__ bm,
        float* __restrict__ m_all) {
    __shared__ float h2l[D], cl[D], sc[NSTEP], red[64];
    int s = blockIdx.x, t = threadIdx.x;
    h2l[t]       = h2s[(size_t)s * D + t];
    h2l[t + 256] = h2s[(size_t)s * D + t + 256];
    __syncthreads();

    if (t < NSTEP) {                    // scores[j] = fencs[j] . h2
        float acc = 0.f;
        const float4* fr = (const float4*)(fencs + (size_t)t * D);
        const float4* hr = (const float4*)h2l;
        #pragma unroll 8
        for (int k4 = 0; k4 < D / 4; k4++) {
            float4 f = fr[k4], hh = hr[k4];
            acc += f.x*hh.x + f.y*hh.y + f.z*hh.z + f.w*hh.w;
        }
        sc[t] = acc;
    }
    __syncthreads();
    if (t < 64) {
        float m = fmaxf(sc[t], sc[t + 64]);
        for (int off = 32; off; off >>= 1) m = fmaxf(m, __shfl_xor(m, off));
        if (t == 0) red[0] = m;
    }
    __syncthreads();
    float mx = red[0];
    __syncthreads();
    if (t < NSTEP) sc[t] = expf(sc[t] - mx);
    __syncthreads();
    if (t < 64) {
        float v = sc[t] + sc[t + 64];
        for (int off = 32; off; off >>= 1) v += __shfl_xor(v, off);
        if (t == 0) red[0] = v;
    }
    __syncthreads();
    float inv = 1.0f / red[0];

    for (int rep = 0; rep < 2; rep++) {         // c[k] = sum_j alpha[j]*fencs[j][k]
        int k = t + rep * 256;
        float acc = 0.f;
        for (int j = 0; j < NSTEP; j++) acc += sc[j] * fencs[(size_t)j * D + k];
        cl[k] = acc * inv;
    }
    __syncthreads();

    for (int rep = 0; rep < 2; rep++) {         // m[o] = tanh(Wm[o,:512].c + Wm[o,512:].h2 + bm)
        int o = t + rep * 256;
        float acc = bm[o];
        const float4* wr = (const float4*)(Wm + (size_t)o * 2 * D);
        const float4* cr = (const float4*)cl;
        const float4* hr = (const float4*)h2l;
        #pragma unroll 4
        for (int k4 = 0; k4 < D / 4; k4++) {
            float4 w = wr[k4], c = cr[k4];
            acc += w.x*c.x + w.y*c.y + w.z*c.z + w.w*c.w;
        }
        #pragma unroll 4
        for (int k4 = 0; k4 < D / 4; k4++) {
            float4 w = wr[D/4 + k4], hh = hr[k4];
            acc += w.x*hh.x + w.y*hh.y + w.z*hh.z + w.w*hh.w;
        }
        m_all[(size_t)s * D + o] = tanhf(acc);
    }
}

// ---- K4: logits tile GEMM (128 steps x 128 vocab, K=512) + fused row max/sumexp ----
__global__ __launch_bounds__(256) void k_logits(
        const float* __restrict__ m_all, const float* __restrict__ Wo,
        const float* __restrict__ bo, const int* __restrict__ enums,
        float* __restrict__ pmax, float* __restrict__ psum, float* __restrict__ pick) {
    __shared__ float a_s[32 * LDK], b_s[32 * LDK];
    int b = blockIdx.x, t = threadIdx.x;
    int v0 = b * VTILE;
    int ti = t >> 4, tj = t & 15;
    int lk = t & 31, lr = t >> 5;
    float acc[8][8] = {};

    for (int kc = 0; kc < 16; kc++) {
        int k0 = kc * 32;
        #pragma unroll
        for (int ps = 0; ps < 16; ps++) {
            int row = ps * 8 + lr;
            a_s[lk * LDK + row] = m_all[(size_t)row * D + k0 + lk];
            int v = v0 + row;
            b_s[lk * LDK + row] = (v < EVOC) ? Wo[(size_t)v * D + k0 + lk] : 0.f;
        }
        __syncthreads();
        #pragma unroll
        for (int k = 0; k < 32; k++) {
            const float4* ar = (const float4*)(a_s + k * LDK + ti * 8);
            float4 av0 = ar[0], av1 = ar[1];
            const float4* br = (const float4*)(b_s + k * LDK + tj * 8);
            float4 bv0 = br[0], bv1 = br[1];
            float av[8] = {av0.x, av0.y, av0.z, av0.w, av1.x, av1.y, av1.z, av1.w};
            float bv[8] = {bv0.x, bv0.y, bv0.z, bv0.w, bv1.x, bv1.y, bv1.z, bv1.w};
            #pragma unroll
            for (int i = 0; i < 8; i++)
                #pragma unroll
                for (int j = 0; j < 8; j++)
                    acc[i][j] += av[i] * bv[j];
        }
        __syncthreads();
    }

    #pragma unroll
    for (int i = 0; i < 8; i++) {
        int s = ti * 8 + i;
        float l[8];
        float mx = -1e30f;
        #pragma unroll
        for (int j = 0; j < 8; j++) {
            int v = v0 + tj * 8 + j;
            l[j] = (v < EVOC) ? acc[i][j] + bo[v] : -1e30f;
            mx = fmaxf(mx, l[j]);
        }
        for (int m = 1; m < 16; m <<= 1) mx = fmaxf(mx, __shfl_xor(mx, m));
        float sm = 0.f;
        #pragma unroll
        for (int j = 0; j < 8; j++) {
            int v = v0 + tj * 8 + j;
            if (v < EVOC) sm += expf(l[j] - mx);
        }
        for (int m = 1; m < 16; m <<= 1) sm += __shfl_xor(sm, m);
        if (tj == 0) { pmax[b * NSTEP + s] = mx; psum[b * NSTEP + s] = sm; }
        int tgt = enums[s + 1];
        if (tgt >= v0 && tgt < v0 + VTILE) {
            int jj = tgt - v0;
            if ((jj >> 3) == tj) pick[s] = l[jj & 7];
        }
    }
}

// ---- K5: combine partial logsumexps, pick target logprobs, sum ----
__global__ void k_final(const float* __restrict__ pmax, const float* __restrict__ psum,
                        const float* __restrict__ pick, float* __restrict__ out) {
    __shared__ float red[NSTEP];
    int t = threadIdx.x;     // 128 threads, one per decoder step
    float M = -1e30f;
    for (int b = 0; b < NBV; b++) M = fmaxf(M, pmax[b * NSTEP + t]);
    float S = 0.f;
    for (int b = 0; b < NBV; b++) S += psum[b * NSTEP + t] * expf(pmax[b * NSTEP + t] - M);
    red[t] = pick[t] - (M + logf(S));
    __syncthreads();
    for (int off = 64; off > 0; off >>= 1) {
        if (t < off) red[t] += red[t + off];
        __syncthreads();
    }
    if (t == 0) out[0] = red[0];
}

extern "C" void kernel_launch(void* const* d_in, const int* in_sizes, int n_in,
                              void* d_out, int out_size, void* d_ws, size_t ws_size,
                              hipStream_t stream) {
    const int*   fnums = (const int*)  d_in[0];
    const int*   enums = (const int*)  d_in[1];
    const float* emb_f = (const float*)d_in[2];
    const float* Wih_e = (const float*)d_in[3];
    const float* Whh_e = (const float*)d_in[4];
    const float* b_e   = (const float*)d_in[5];
    const float* h0_e  = (const float*)d_in[6];
    const float* emb_d = (const float*)d_in[7];
    const float* Wih_d = (const float*)d_in[8];
    const float* Whh_d = (const float*)d_in[9];
    const float* b_d   = (const float*)d_in[10];
    const float* h0_d  = (const float*)d_in[11];
    const float* Wm    = (const float*)d_in[12];
    const float* bm    = (const float*)d_in[13];
    const float* Wo    = (const float*)d_in[14];
    const float* bo    = (const float*)d_in[15];

    float* ws = (float*)d_ws;
    float* pre_e = ws;                 // 128*512
    float* pre_d = ws + 65536;
    float* fencs = ws + 131072;
    float* h2s   = ws + 196608;
    float* m_all = ws + 262144;
    float* pmax  = ws + 327680;        // 391*128
    float* psum  = ws + 377728;
    float* pick  = ws + 427776;        // 128
    float* qsc   = ws + 427904;        // 1024 row scales
    int8_t* q8   = (int8_t*)(ws + 428928);   // 2 x 256 KB int8 weights

    k_quant<<<dim3(1024), dim3(64), 0, stream>>>(Whh_e, Whh_d, q8, qsc);
    k_pre<<<dim3(256), dim3(256), 0, stream>>>(fnums, enums, emb_f, emb_d,
                                               Wih_e, Wih_d, b_e, b_d, pre_e, pre_d);
    k_scan<<<dim3(2), dim3(1024), 0, stream>>>(q8, qsc, pre_e, pre_d, h0_e, h0_d, fencs, h2s);
    k_att<<<dim3(NSTEP), dim3(256), 0, stream>>>(fencs, h2s, Wm, bm, m_all);
    k_logits<<<dim3(NBV), dim3(256), 0, stream>>>(m_all, Wo, bo, enums, pmax, psum, pick);
    k_final<<<dim3(1), dim3(NSTEP), 0, stream>>>(pmax, psum, pick, (float*)d_out);
}

// Round 5
// 451.966 us; speedup vs baseline: 6.4915x; 1.5681x over previous
//
#include <hip/hip_runtime.h>
#include <stdint.h>

#define D      512
#define NSTEP  128          // SRC steps == decoder steps (TGT-1)
#define EVOC   50000
#define VTILE  128
#define NBV    ((EVOC + VTILE - 1) / VTILE)   // 391
#define LDA_W  36           // A LDS row stride in u32 words (144 B, 16B-aligned)
#define LDB_W  129          // B LDS kw-row stride in u32 words (128 cols + 1 pad)

// ---- int8 dot4 (v_dot4_i32_i8) ----
__device__ inline int sdot4(int a, int b, int c) {
#if __has_builtin(__builtin_amdgcn_sdot4)
    return __builtin_amdgcn_sdot4(a, b, c, false);
#else
    int r = c;
    r += (int)(int8_t)(a)       * (int)(int8_t)(b);
    r += (int)(int8_t)(a >> 8)  * (int)(int8_t)(b >> 8);
    r += (int)(int8_t)(a >> 16) * (int)(int8_t)(b >> 16);
    r += (int)(int8_t)(a >> 24) * (int)(int8_t)(b >> 24);
    return r;
#endif
}

__device__ inline uint32_t pack4(float a, float b, float c, float d, float inv) {
    return  ((uint32_t)(uint8_t)(int8_t)__float2int_rn(a * inv)) |
            ((uint32_t)(uint8_t)(int8_t)__float2int_rn(b * inv) << 8) |
            ((uint32_t)(uint8_t)(int8_t)__float2int_rn(c * inv) << 16) |
            ((uint32_t)(uint8_t)(int8_t)__float2int_rn(d * inv) << 24);
}

// ---- K0: per-row symmetric int8 quantization of Whh_e / Whh_d ----
__global__ __launch_bounds__(64) void k_quant(
        const float* __restrict__ We, const float* __restrict__ Wd,
        int8_t* __restrict__ q8, float* __restrict__ qsc) {
    int bid = blockIdx.x;                 // 0..1023
    int which = bid >> 9, row = bid & 511;
    const float* W = which ? Wd : We;
    int lane = threadIdx.x;
    const float* src = W + (size_t)row * D + lane * 8;
    float4 v0 = ((const float4*)src)[0];
    float4 v1 = ((const float4*)src)[1];
    float m = fmaxf(fmaxf(fmaxf(fabsf(v0.x), fabsf(v0.y)), fmaxf(fabsf(v0.z), fabsf(v0.w))),
                    fmaxf(fmaxf(fabsf(v1.x), fabsf(v1.y)), fmaxf(fabsf(v1.z), fabsf(v1.w))));
    for (int off = 32; off; off >>= 1) m = fmaxf(m, __shfl_xor(m, off));
    float inv = (m > 0.f) ? 127.f / m : 0.f;
    uint32_t lo = pack4(v0.x, v0.y, v0.z, v0.w, inv);
    uint32_t hi = pack4(v1.x, v1.y, v1.z, v1.w, inv);
    uint2* dst = (uint2*)(q8 + (size_t)which * D * D + (size_t)row * D);
    dst[lane] = make_uint2(lo, hi);
    if (lane == 0) qsc[which * D + row] = m / 127.f;
}

// ---- K0b: per-row int8 quantization of Wo (50000 x 512), 4 rows/block ----
__global__ __launch_bounds__(256) void k_quant_wo(
        const float* __restrict__ Wo, int8_t* __restrict__ woq,
        float* __restrict__ wosc) {
    int row = blockIdx.x * 4 + (threadIdx.x >> 6);
    if (row >= EVOC) return;
    int lane = threadIdx.x & 63;
    const float4* src = (const float4*)(Wo + (size_t)row * D);
    float4 v0 = src[lane];
    float4 v1 = src[lane + 64];
    float m = fmaxf(fmaxf(fmaxf(fabsf(v0.x), fabsf(v0.y)), fmaxf(fabsf(v0.z), fabsf(v0.w))),
                    fmaxf(fmaxf(fabsf(v1.x), fabsf(v1.y)), fmaxf(fabsf(v1.z), fabsf(v1.w))));
    for (int off = 32; off; off >>= 1) m = fmaxf(m, __shfl_xor(m, off));
    float inv = (m > 0.f) ? 127.f / m : 0.f;
    uint32_t* dst = (uint32_t*)(woq + (size_t)row * D);
    dst[lane]      = pack4(v0.x, v0.y, v0.z, v0.w, inv);
    dst[lane + 64] = pack4(v1.x, v1.y, v1.z, v1.w, inv);
    if (lane == 0) wosc[row] = m / 127.f;
}

// ---- K1: pre[s][o] = emb[idx[s]] . Wih[o,:] + b[o]   (both enc & dec) ----
__global__ __launch_bounds__(256) void k_pre(
        const int* __restrict__ fnums, const int* __restrict__ enums,
        const float* __restrict__ emb_f, const float* __restrict__ emb_d,
        const float* __restrict__ Wih_e, const float* __restrict__ Wih_d,
        const float* __restrict__ b_e, const float* __restrict__ b_d,
        float* __restrict__ pre_e, float* __restrict__ pre_d) {
    __shared__ float xl[D];
    int bb = blockIdx.x;            // 0..255 : 128 enc + 128 dec
    int kind = bb >> 7, s = bb & 127;
    const float* emb = kind ? emb_d : emb_f;
    int idx          = kind ? enums[s] : fnums[s];
    const float* W   = kind ? Wih_d : Wih_e;
    const float* b   = kind ? b_d : b_e;
    float* pre       = kind ? pre_d : pre_e;
    int t = threadIdx.x;
    xl[t]       = emb[(size_t)idx * D + t];
    xl[t + 256] = emb[(size_t)idx * D + t + 256];
    __syncthreads();
    for (int rep = 0; rep < 2; rep++) {
        int o = t + rep * 256;
        float acc = b[o];
        const float4* Wr = (const float4*)(W + (size_t)o * D);
        #pragma unroll 8
        for (int k4 = 0; k4 < D / 4; k4++) {
            float4 w = Wr[k4];
            acc += w.x * xl[4*k4] + w.y * xl[4*k4+1] + w.z * xl[4*k4+2] + w.w * xl[4*k4+3];
        }
        pre[(size_t)s * D + o] = acc;
    }
}

// ---- K2: the two sequential scans, int8 x dot4 (unchanged from round 4) ----
__global__ __launch_bounds__(1024) void k_scan(
        const int8_t* __restrict__ q8, const float* __restrict__ qsc,
        const float* __restrict__ pre_e, const float* __restrict__ pre_d,
        const float* __restrict__ h0_e, const float* __restrict__ h0_d,
        float* __restrict__ fencs, float* __restrict__ h2s) {
    __shared__ int8_t hq[2][D];
    int t = threadIdx.x;
    int r = t >> 1, hf = t & 1;
    int which = blockIdx.x;
    const int8_t* w8 = q8 + (size_t)which * D * D;
    const float*  pre = which ? pre_d : pre_e;
    const float*  h0  = which ? h0_d : h0_e;
    float*        hs  = which ? h2s : fencs;
    float sw = qsc[which * D + r] * (1.f / 127.f);

    uint32_t w[64];
    const uint4* wr = (const uint4*)(w8 + (size_t)r * D + hf * 256);
    #pragma unroll
    for (int i = 0; i < 16; i++) {
        uint4 v = wr[i];
        w[4*i] = v.x; w[4*i+1] = v.y; w[4*i+2] = v.z; w[4*i+3] = v.w;
    }

    if (hf == 0) {
        float h0v = fminf(fmaxf(h0[r], -0.999f), 0.999f);
        hq[0][r] = (int8_t)__float2int_rn(h0v * 127.f);
    }
    __syncthreads();

    int p = 0;
    for (int step = 0; step < NSTEP; step++) {
        float prev = pre[(size_t)step * D + r];    // same addr for lane pair (broadcast)
        const uint4* hv = (const uint4*)(&hq[p][hf * 256]);
        int a0 = 0, a1 = 0, a2 = 0, a3 = 0;
        #pragma unroll
        for (int i = 0; i < 16; i++) {
            uint4 hx = hv[i];
            a0 = sdot4((int)w[4*i+0], (int)hx.x, a0);
            a1 = sdot4((int)w[4*i+1], (int)hx.y, a1);
            a2 = sdot4((int)w[4*i+2], (int)hx.z, a2);
            a3 = sdot4((int)w[4*i+3], (int)hx.w, a3);
        }
        int acc = (a0 + a1) + (a2 + a3);
        acc += __shfl_xor(acc, 1);                 // combine the two half-rows
        if (hf == 0) {
            float h2 = tanhf(prev + (float)acc * sw);
            hs[(size_t)step * D + r] = h2;
            hq[p ^ 1][r] = (int8_t)__float2int_rn(h2 * 127.f);
        }
        p ^= 1;
        __syncthreads();
    }
}

// ---- K3: per decoder step: attention + m = tanh([c,h2] @ Wm^T + bm) -> int8 ----
__global__ __launch_bounds__(256) void k_att(
        const float* __restrict__ fencs, const float* __restrict__ h2s,
        const float* __restrict__ Wm, const float* __restrict__ bm,
        int8_t* __restrict__ mq) {
    __shared__ float h2l[D], cl[D], sc[NSTEP], red[64];
    int s = blockIdx.x, t = threadIdx.x;
    h2l[t]       = h2s[(size_t)s * D + t];
    h2l[t + 256] = h2s[(size_t)s * D + t + 256];
    __syncthreads();

    if (t < NSTEP) {                    // scores[j] = fencs[j] . h2
        float acc = 0.f;
        const float4* fr = (const float4*)(fencs + (size_t)t * D);
        const float4* hr = (const float4*)h2l;
        #pragma unroll 8
        for (int k4 = 0; k4 < D / 4; k4++) {
            float4 f = fr[k4], hh = hr[k4];
            acc += f.x*hh.x + f.y*hh.y + f.z*hh.z + f.w*hh.w;
        }
        sc[t] = acc;
    }
    __syncthreads();
    if (t < 64) {
        float m = fmaxf(sc[t], sc[t + 64]);
        for (int off = 32; off; off >>= 1) m = fmaxf(m, __shfl_xor(m, off));
        if (t == 0) red[0] = m;
    }
    __syncthreads();
    float mx = red[0];
    __syncthreads();
    if (t < NSTEP) sc[t] = expf(sc[t] - mx);
    __syncthreads();
    if (t < 64) {
        float v = sc[t] + sc[t + 64];
        for (int off = 32; off; off >>= 1) v += __shfl_xor(v, off);
        if (t == 0) red[0] = v;
    }
    __syncthreads();
    float inv = 1.0f / red[0];

    for (int rep = 0; rep < 2; rep++) {         // c[k] = sum_j alpha[j]*fencs[j][k]
        int k = t + rep * 256;
        float acc = 0.f;
        for (int j = 0; j < NSTEP; j++) acc += sc[j] * fencs[(size_t)j * D + k];
        cl[k] = acc * inv;
    }
    __syncthreads();

    for (int rep = 0; rep < 2; rep++) {         // m[o] = tanh(Wm[o,:512].c + Wm[o,512:].h2 + bm)
        int o = t + rep * 256;
        float acc = bm[o];
        const float4* wr = (const float4*)(Wm + (size_t)o * 2 * D);
        const float4* cr = (const float4*)cl;
        const float4* hr = (const float4*)h2l;
        #pragma unroll 4
        for (int k4 = 0; k4 < D / 4; k4++) {
            float4 w = wr[k4], c = cr[k4];
            acc += w.x*c.x + w.y*c.y + w.z*c.z + w.w*c.w;
        }
        #pragma unroll 4
        for (int k4 = 0; k4 < D / 4; k4++) {
            float4 w = wr[D/4 + k4], hh = hr[k4];
            acc += w.x*hh.x + w.y*hh.y + w.z*hh.z + w.w*hh.w;
        }
        float mval = tanhf(acc);
        mq[(size_t)s * D + o] = (int8_t)__float2int_rn(mval * 127.f);
    }
}

// ---- K4: int8 logits GEMM (128 steps x 128 vocab, K=512) + fused row max/sumexp ----
// A LDS [row][36 u32-words] (16B-aligned rows; b128 reads broadcast, 2-way=free)
// B LDS [kw][129 cols] (scalar b32 reads, lane stride 1 -> 32 banks, conflict-free)
__global__ __launch_bounds__(512) void k_logits(
        const int8_t* __restrict__ mq, const int8_t* __restrict__ woq,
        const float* __restrict__ wosc, const float* __restrict__ bo,
        const int* __restrict__ enums,
        float* __restrict__ pmax, float* __restrict__ psum, float* __restrict__ pick) {
    __shared__ uint32_t a_s[128 * LDA_W];   // 18.4 KB
    __shared__ uint32_t b_s[32 * LDB_W];    // 16.5 KB
    int b = blockIdx.x, t = threadIdx.x;
    int v0 = b * VTILE;
    int ti = t >> 5, tj = t & 31;           // out: rows ti*8+i, cols tj+32*jj
    int lrow = t >> 3, lq = t & 7;          // staging: 64 rows/rep, 8 16B-quads/row
    int acc[8][4] = {};

    for (int kc = 0; kc < 4; kc++) {        // K chunks of 128 int8 (32 words)
        #pragma unroll
        for (int rep = 0; rep < 2; rep++) {
            int row = lrow + rep * 64;
            uint4 av = *(const uint4*)(mq + (size_t)row * D + kc * 128 + lq * 16);
            *(uint4*)&a_s[row * LDA_W + lq * 4] = av;
            int v = v0 + row;
            uint4 bv = (v < EVOC)
                ? *(const uint4*)(woq + (size_t)v * D + kc * 128 + lq * 16)
                : make_uint4(0u, 0u, 0u, 0u);
            b_s[(lq*4+0) * LDB_W + row] = bv.x;
            b_s[(lq*4+1) * LDB_W + row] = bv.y;
            b_s[(lq*4+2) * LDB_W + row] = bv.z;
            b_s[(lq*4+3) * LDB_W + row] = bv.w;
        }
        __syncthreads();
        #pragma unroll
        for (int q = 0; q < 8; q++) {
            uint4 aw[8];
            #pragma unroll
            for (int i = 0; i < 8; i++)
                aw[i] = *(const uint4*)&a_s[(ti*8 + i) * LDA_W + q*4];
            #pragma unroll
            for (int k4 = 0; k4 < 4; k4++) {
                uint32_t bw[4];
                #pragma unroll
                for (int jj = 0; jj < 4; jj++)
                    bw[jj] = b_s[(q*4 + k4) * LDB_W + tj + 32*jj];
                #pragma unroll
                for (int i = 0; i < 8; i++) {
                    uint32_t a = (k4 == 0) ? aw[i].x : (k4 == 1) ? aw[i].y
                               : (k4 == 2) ? aw[i].z : aw[i].w;
                    #pragma unroll
                    for (int jj = 0; jj < 4; jj++)
                        acc[i][jj] = sdot4((int)a, (int)bw[jj], acc[i][jj]);
                }
            }
        }
        __syncthreads();
    }

    // epilogue: per-column scale + bias, then per-row max/sumexp across 32 lanes
    float sw4[4], bo4[4];
    int vld[4];
    #pragma unroll
    for (int jj = 0; jj < 4; jj++) {
        int v = v0 + tj + 32*jj;
        vld[jj] = (v < EVOC);
        sw4[jj] = vld[jj] ? wosc[v] * (1.f/127.f) : 0.f;
        bo4[jj] = vld[jj] ? bo[v] : 0.f;
    }
    #pragma unroll
    for (int i = 0; i < 8; i++) {
        int s = ti * 8 + i;
        float l[4];
        float mx = -1e30f;
        #pragma unroll
        for (int jj = 0; jj < 4; jj++) {
            l[jj] = vld[jj] ? (float)acc[i][jj] * sw4[jj] + bo4[jj] : -1e30f;
            mx = fmaxf(mx, l[jj]);
        }
        #pragma unroll
        for (int off = 1; off < 32; off <<= 1) mx = fmaxf(mx, __shfl_xor(mx, off));
        float sm = 0.f;
        #pragma unroll
        for (int jj = 0; jj < 4; jj++)
            if (vld[jj]) sm += expf(l[jj] - mx);
        #pragma unroll
        for (int off = 1; off < 32; off <<= 1) sm += __shfl_xor(sm, off);
        if (tj == 0) { pmax[b * NSTEP + s] = mx; psum[b * NSTEP + s] = sm; }
        int tgt = enums[s + 1];
        if (tgt >= v0 && tgt < v0 + VTILE) {
            int c = tgt - v0;
            if ((c & 31) == tj) pick[s] = l[c >> 5];
        }
    }
}

// ---- K5: combine partial logsumexps, pick target logprobs, sum ----
__global__ void k_final(const float* __restrict__ pmax, const float* __restrict__ psum,
                        const float* __restrict__ pick, float* __restrict__ out) {
    __shared__ float red[NSTEP];
    int t = threadIdx.x;     // 128 threads, one per decoder step
    float M = -1e30f;
    for (int b = 0; b < NBV; b++) M = fmaxf(M, pmax[b * NSTEP + t]);
    float S = 0.f;
    for (int b = 0; b < NBV; b++) S += psum[b * NSTEP + t] * expf(pmax[b * NSTEP + t] - M);
    red[t] = pick[t] - (M + logf(S));
    __syncthreads();
    for (int off = 64; off > 0; off >>= 1) {
        if (t < off) red[t] += red[t + off];
        __syncthreads();
    }
    if (t == 0) out[0] = red[0];
}

extern "C" void kernel_launch(void* const* d_in, const int* in_sizes, int n_in,
                              void* d_out, int out_size, void* d_ws, size_t ws_size,
                              hipStream_t stream) {
    const int*   fnums = (const int*)  d_in[0];
    const int*   enums = (const int*)  d_in[1];
    const float* emb_f = (const float*)d_in[2];
    const float* Wih_e = (const float*)d_in[3];
    const float* Whh_e = (const float*)d_in[4];
    const float* b_e   = (const float*)d_in[5];
    const float* h0_e  = (const float*)d_in[6];
    const float* emb_d = (const float*)d_in[7];
    const float* Wih_d = (const float*)d_in[8];
    const float* Whh_d = (const float*)d_in[9];
    const float* b_d   = (const float*)d_in[10];
    const float* h0_d  = (const float*)d_in[11];
    const float* Wm    = (const float*)d_in[12];
    const float* bm    = (const float*)d_in[13];
    const float* Wo    = (const float*)d_in[14];
    const float* bo    = (const float*)d_in[15];

    float* ws = (float*)d_ws;
    float* pre_e = ws;                       // 65536
    float* pre_d = ws + 65536;               // 65536
    float* fencs = ws + 131072;              // 65536
    float* h2s   = ws + 196608;              // 65536
    float* pmax  = ws + 262144;              // 50048
    float* psum  = ws + 312192;              // 50048
    float* pick  = ws + 362240;              // 128
    float* qsc   = ws + 362368;              // 1024
    int8_t* q8   = (int8_t*)(ws + 363392);   // 512 KB scan weights
    float* wosc  = ws + 494464;              // 50048
    int8_t* mq   = (int8_t*)(ws + 544512);   // 64 KB
    int8_t* woq  = (int8_t*)(ws + 560896);   // 25.6 MB

    k_quant<<<dim3(1024), dim3(64), 0, stream>>>(Whh_e, Whh_d, q8, qsc);
    k_quant_wo<<<dim3((EVOC + 3) / 4), dim3(256), 0, stream>>>(Wo, woq, wosc);
    k_pre<<<dim3(256), dim3(256), 0, stream>>>(fnums, enums, emb_f, emb_d,
                                               Wih_e, Wih_d, b_e, b_d, pre_e, pre_d);
    k_scan<<<dim3(2), dim3(1024), 0, stream>>>(q8, qsc, pre_e, pre_d, h0_e, h0_d, fencs, h2s);
    k_att<<<dim3(NSTEP), dim3(256), 0, stream>>>(fencs, h2s, Wm, bm, mq);
    k_logits<<<dim3(NBV), dim3(512), 0, stream>>>(mq, woq, wosc, bo, enums, pmax, psum, pick);
    k_final<<<dim3(1), dim3(NSTEP), 0, stream>>>(pmax, psum, pick, (float*)d_out);
}

// Round 6
// 451.546 us; speedup vs baseline: 6.4976x; 1.0009x over previous
//
#include <hip/hip_runtime.h>
#include <stdint.h>

#define D      512
#define NSTEP  128          // SRC steps == decoder steps (TGT-1)
#define EVOC   50000
#define VTILE  128
#define NBV    ((EVOC + VTILE - 1) / VTILE)   // 391
#define LDA_W  36           // A LDS row stride in u32 words (144 B, 16B-aligned)
#define LDB_W  129          // B LDS kw-row stride in u32 words (128 cols + 1 pad)

// ---- int8 dot4 (v_dot4_i32_i8) ----
__device__ inline int sdot4(int a, int b, int c) {
#if __has_builtin(__builtin_amdgcn_sdot4)
    return __builtin_amdgcn_sdot4(a, b, c, false);
#else
    int r = c;
    r += (int)(int8_t)(a)       * (int)(int8_t)(b);
    r += (int)(int8_t)(a >> 8)  * (int)(int8_t)(b >> 8);
    r += (int)(int8_t)(a >> 16) * (int)(int8_t)(b >> 16);
    r += (int)(int8_t)(a >> 24) * (int)(int8_t)(b >> 24);
    return r;
#endif
}

__device__ inline uint32_t pack4(float a, float b, float c, float d, float inv) {
    return  ((uint32_t)(uint8_t)(int8_t)__float2int_rn(a * inv)) |
            ((uint32_t)(uint8_t)(int8_t)__float2int_rn(b * inv) << 8) |
            ((uint32_t)(uint8_t)(int8_t)__float2int_rn(c * inv) << 16) |
            ((uint32_t)(uint8_t)(int8_t)__float2int_rn(d * inv) << 24);
}

// ---- K0: per-row symmetric int8 quantization of Whh_e / Whh_d ----
__global__ __launch_bounds__(64) void k_quant(
        const float* __restrict__ We, const float* __restrict__ Wd,
        int8_t* __restrict__ q8, float* __restrict__ qsc) {
    int bid = blockIdx.x;                 // 0..1023
    int which = bid >> 9, row = bid & 511;
    const float* W = which ? Wd : We;
    int lane = threadIdx.x;
    const float* src = W + (size_t)row * D + lane * 8;
    float4 v0 = ((const float4*)src)[0];
    float4 v1 = ((const float4*)src)[1];
    float m = fmaxf(fmaxf(fmaxf(fabsf(v0.x), fabsf(v0.y)), fmaxf(fabsf(v0.z), fabsf(v0.w))),
                    fmaxf(fmaxf(fabsf(v1.x), fabsf(v1.y)), fmaxf(fabsf(v1.z), fabsf(v1.w))));
    for (int off = 32; off; off >>= 1) m = fmaxf(m, __shfl_xor(m, off));
    float inv = (m > 0.f) ? 127.f / m : 0.f;
    uint32_t lo = pack4(v0.x, v0.y, v0.z, v0.w, inv);
    uint32_t hi = pack4(v1.x, v1.y, v1.z, v1.w, inv);
    uint2* dst = (uint2*)(q8 + (size_t)which * D * D + (size_t)row * D);
    dst[lane] = make_uint2(lo, hi);
    if (lane == 0) qsc[which * D + row] = m / 127.f;
}

// ---- K0b: per-row int8 quantization of Wo (50000 x 512), 4 rows/block ----
__global__ __launch_bounds__(256) void k_quant_wo(
        const float* __restrict__ Wo, int8_t* __restrict__ woq,
        float* __restrict__ wosc) {
    int row = blockIdx.x * 4 + (threadIdx.x >> 6);
    if (row >= EVOC) return;
    int lane = threadIdx.x & 63;
    const float4* src = (const float4*)(Wo + (size_t)row * D);
    float4 v0 = src[lane];
    float4 v1 = src[lane + 64];
    float m = fmaxf(fmaxf(fmaxf(fabsf(v0.x), fabsf(v0.y)), fmaxf(fabsf(v0.z), fabsf(v0.w))),
                    fmaxf(fmaxf(fabsf(v1.x), fabsf(v1.y)), fmaxf(fabsf(v1.z), fabsf(v1.w))));
    for (int off = 32; off; off >>= 1) m = fmaxf(m, __shfl_xor(m, off));
    float inv = (m > 0.f) ? 127.f / m : 0.f;
    uint32_t* dst = (uint32_t*)(woq + (size_t)row * D);
    dst[lane]      = pack4(v0.x, v0.y, v0.z, v0.w, inv);
    dst[lane + 64] = pack4(v1.x, v1.y, v1.z, v1.w, inv);
    if (lane == 0) wosc[row] = m / 127.f;
}

// ---- K1: pre[s][o] = emb[idx[s]] . Wih[o,:] + b[o]   (both enc & dec) ----
__global__ __launch_bounds__(256) void k_pre(
        const int* __restrict__ fnums, const int* __restrict__ enums,
        const float* __restrict__ emb_f, const float* __restrict__ emb_d,
        const float* __restrict__ Wih_e, const float* __restrict__ Wih_d,
        const float* __restrict__ b_e, const float* __restrict__ b_d,
        float* __restrict__ pre_e, float* __restrict__ pre_d) {
    __shared__ float xl[D];
    int bb = blockIdx.x;            // 0..255 : 128 enc + 128 dec
    int kind = bb >> 7, s = bb & 127;
    const float* emb = kind ? emb_d : emb_f;
    int idx          = kind ? enums[s] : fnums[s];
    const float* W   = kind ? Wih_d : Wih_e;
    const float* b   = kind ? b_d : b_e;
    float* pre       = kind ? pre_d : pre_e;
    int t = threadIdx.x;
    xl[t]       = emb[(size_t)idx * D + t];
    xl[t + 256] = emb[(size_t)idx * D + t + 256];
    __syncthreads();
    for (int rep = 0; rep < 2; rep++) {
        int o = t + rep * 256;
        float acc = b[o];
        const float4* Wr = (const float4*)(W + (size_t)o * D);
        #pragma unroll 8
        for (int k4 = 0; k4 < D / 4; k4++) {
            float4 w = Wr[k4];
            acc += w.x * xl[4*k4] + w.y * xl[4*k4+1] + w.z * xl[4*k4+2] + w.w * xl[4*k4+3];
        }
        pre[(size_t)s * D + o] = acc;
    }
}

// ---- K2: the two sequential scans, int8 x dot4. ----
// __launch_bounds__(1024, 1): without it the allocator targeted 2 blocks/CU
// (64-VGPR cap) and spilled the 64-u32 weight array to scratch (VGPR_Count=44,
// 183us). "1" is safe under BOTH second-arg interpretations (min-blocks/CU or
// min-waves/EU): either yields the full 128-VGPR cap for a 16-wave block, and
// 64 weight regs + ~44 working regs fit with no spill.
__global__ __launch_bounds__(1024, 1) void k_scan(
        const int8_t* __restrict__ q8, const float* __restrict__ qsc,
        const float* __restrict__ pre_e, const float* __restrict__ pre_d,
        const float* __restrict__ h0_e, const float* __restrict__ h0_d,
        float* __restrict__ fencs, float* __restrict__ h2s) {
    __shared__ int8_t hq[2][D];
    int t = threadIdx.x;
    int r = t >> 1, hf = t & 1;
    int which = blockIdx.x;
    const int8_t* w8 = q8 + (size_t)which * D * D;
    const float*  pre = which ? pre_d : pre_e;
    const float*  h0  = which ? h0_d : h0_e;
    float*        hs  = which ? h2s : fencs;
    float sw = qsc[which * D + r] * (1.f / 127.f);

    uint32_t w[64];
    const uint4* wr = (const uint4*)(w8 + (size_t)r * D + hf * 256);
    #pragma unroll
    for (int i = 0; i < 16; i++) {
        uint4 v = wr[i];
        w[4*i] = v.x; w[4*i+1] = v.y; w[4*i+2] = v.z; w[4*i+3] = v.w;
    }

    if (hf == 0) {
        float h0v = fminf(fmaxf(h0[r], -0.999f), 0.999f);
        hq[0][r] = (int8_t)__float2int_rn(h0v * 127.f);
    }
    __syncthreads();

    int p = 0;
    for (int step = 0; step < NSTEP; step++) {
        float prev = pre[(size_t)step * D + r];    // same addr for lane pair (broadcast)
        const uint4* hv = (const uint4*)(&hq[p][hf * 256]);
        int a0 = 0, a1 = 0, a2 = 0, a3 = 0;
        #pragma unroll
        for (int i = 0; i < 16; i++) {
            uint4 hx = hv[i];
            a0 = sdot4((int)w[4*i+0], (int)hx.x, a0);
            a1 = sdot4((int)w[4*i+1], (int)hx.y, a1);
            a2 = sdot4((int)w[4*i+2], (int)hx.z, a2);
            a3 = sdot4((int)w[4*i+3], (int)hx.w, a3);
        }
        int acc = (a0 + a1) + (a2 + a3);
        acc += __shfl_xor(acc, 1);                 // combine the two half-rows
        if (hf == 0) {
            float h2 = tanhf(prev + (float)acc * sw);
            hs[(size_t)step * D + r] = h2;
            hq[p ^ 1][r] = (int8_t)__float2int_rn(h2 * 127.f);
        }
        p ^= 1;
        __syncthreads();
    }
}

// ---- K3: per decoder step: attention + m = tanh([c,h2] @ Wm^T + bm) -> int8 ----
__global__ __launch_bounds__(256) void k_att(
        const float* __restrict__ fencs, const float* __restrict__ h2s,
        const float* __restrict__ Wm, const float* __restrict__ bm,
        int8_t* __restrict__ mq) {
    __shared__ float h2l[D], cl[D], sc[NSTEP], red[64];
    int s = blockIdx.x, t = threadIdx.x;
    h2l[t]       = h2s[(size_t)s * D + t];
    h2l[t + 256] = h2s[(size_t)s * D + t + 256];
    __syncthreads();

    if (t < NSTEP) {                    // scores[j] = fencs[j] . h2
        float acc = 0.f;
        const float4* fr = (const float4*)(fencs + (size_t)t * D);
        const float4* hr = (const float4*)h2l;
        #pragma unroll 8
        for (int k4 = 0; k4 < D / 4; k4++) {
            float4 f = fr[k4], hh = hr[k4];
            acc += f.x*hh.x + f.y*hh.y + f.z*hh.z + f.w*hh.w;
        }
        sc[t] = acc;
    }
    __syncthreads();
    if (t < 64) {
        float m = fmaxf(sc[t], sc[t + 64]);
        for (int off = 32; off; off >>= 1) m = fmaxf(m, __shfl_xor(m, off));
        if (t == 0) red[0] = m;
    }
    __syncthreads();
    float mx = red[0];
    __syncthreads();
    if (t < NSTEP) sc[t] = expf(sc[t] - mx);
    __syncthreads();
    if (t < 64) {
        float v = sc[t] + sc[t + 64];
        for (int off = 32; off; off >>= 1) v += __shfl_xor(v, off);
        if (t == 0) red[0] = v;
    }
    __syncthreads();
    float inv = 1.0f / red[0];

    for (int rep = 0; rep < 2; rep++) {         // c[k] = sum_j alpha[j]*fencs[j][k]
        int k = t + rep * 256;
        float acc = 0.f;
        for (int j = 0; j < NSTEP; j++) acc += sc[j] * fencs[(size_t)j * D + k];
        cl[k] = acc * inv;
    }
    __syncthreads();

    for (int rep = 0; rep < 2; rep++) {         // m[o] = tanh(Wm[o,:512].c + Wm[o,512:].h2 + bm)
        int o = t + rep * 256;
        float acc = bm[o];
        const float4* wr = (const float4*)(Wm + (size_t)o * 2 * D);
        const float4* cr = (const float4*)cl;
        const float4* hr = (const float4*)h2l;
        #pragma unroll 4
        for (int k4 = 0; k4 < D / 4; k4++) {
            float4 w = wr[k4], c = cr[k4];
            acc += w.x*c.x + w.y*c.y + w.z*c.z + w.w*c.w;
        }
        #pragma unroll 4
        for (int k4 = 0; k4 < D / 4; k4++) {
            float4 w = wr[D/4 + k4], hh = hr[k4];
            acc += w.x*hh.x + w.y*hh.y + w.z*hh.z + w.w*hh.w;
        }
        float mval = tanhf(acc);
        mq[(size_t)s * D + o] = (int8_t)__float2int_rn(mval * 127.f);
    }
}

// ---- K4: int8 logits GEMM (128 steps x 128 vocab, K=512) + fused row max/sumexp ----
// A LDS [row][36 u32-words] (16B-aligned rows; b128 reads broadcast, 2-way=free)
// B LDS [kw][129 cols] (scalar b32 reads, lane stride 1 -> 32 banks, conflict-free)
__global__ __launch_bounds__(512) void k_logits(
        const int8_t* __restrict__ mq, const int8_t* __restrict__ woq,
        const float* __restrict__ wosc, const float* __restrict__ bo,
        const int* __restrict__ enums,
        float* __restrict__ pmax, float* __restrict__ psum, float* __restrict__ pick) {
    __shared__ uint32_t a_s[128 * LDA_W];   // 18.4 KB
    __shared__ uint32_t b_s[32 * LDB_W];    // 16.5 KB
    int b = blockIdx.x, t = threadIdx.x;
    int v0 = b * VTILE;
    int ti = t >> 5, tj = t & 31;           // out: rows ti*8+i, cols tj+32*jj
    int lrow = t >> 3, lq = t & 7;          // staging: 64 rows/rep, 8 16B-quads/row
    int acc[8][4] = {};

    for (int kc = 0; kc < 4; kc++) {        // K chunks of 128 int8 (32 words)
        #pragma unroll
        for (int rep = 0; rep < 2; rep++) {
            int row = lrow + rep * 64;
            uint4 av = *(const uint4*)(mq + (size_t)row * D + kc * 128 + lq * 16);
            *(uint4*)&a_s[row * LDA_W + lq * 4] = av;
            int v = v0 + row;
            uint4 bv = (v < EVOC)
                ? *(const uint4*)(woq + (size_t)v * D + kc * 128 + lq * 16)
                : make_uint4(0u, 0u, 0u, 0u);
            b_s[(lq*4+0) * LDB_W + row] = bv.x;
            b_s[(lq*4+1) * LDB_W + row] = bv.y;
            b_s[(lq*4+2) * LDB_W + row] = bv.z;
            b_s[(lq*4+3) * LDB_W + row] = bv.w;
        }
        __syncthreads();
        #pragma unroll
        for (int q = 0; q < 8; q++) {
            uint4 aw[8];
            #pragma unroll
            for (int i = 0; i < 8; i++)
                aw[i] = *(const uint4*)&a_s[(ti*8 + i) * LDA_W + q*4];
            #pragma unroll
            for (int k4 = 0; k4 < 4; k4++) {
                uint32_t bw[4];
                #pragma unroll
                for (int jj = 0; jj < 4; jj++)
                    bw[jj] = b_s[(q*4 + k4) * LDB_W + tj + 32*jj];
                #pragma unroll
                for (int i = 0; i < 8; i++) {
                    uint32_t a = (k4 == 0) ? aw[i].x : (k4 == 1) ? aw[i].y
                               : (k4 == 2) ? aw[i].z : aw[i].w;
                    #pragma unroll
                    for (int jj = 0; jj < 4; jj++)
                        acc[i][jj] = sdot4((int)a, (int)bw[jj], acc[i][jj]);
                }
            }
        }
        __syncthreads();
    }

    // epilogue: per-column scale + bias, then per-row max/sumexp across 32 lanes
    float sw4[4], bo4[4];
    int vld[4];
    #pragma unroll
    for (int jj = 0; jj < 4; jj++) {
        int v = v0 + tj + 32*jj;
        vld[jj] = (v < EVOC);
        sw4[jj] = vld[jj] ? wosc[v] * (1.f/127.f) : 0.f;
        bo4[jj] = vld[jj] ? bo[v] : 0.f;
    }
    #pragma unroll
    for (int i = 0; i < 8; i++) {
        int s = ti * 8 + i;
        float l[4];
        float mx = -1e30f;
        #pragma unroll
        for (int jj = 0; jj < 4; jj++) {
            l[jj] = vld[jj] ? (float)acc[i][jj] * sw4[jj] + bo4[jj] : -1e30f;
            mx = fmaxf(mx, l[jj]);
        }
        #pragma unroll
        for (int off = 1; off < 32; off <<= 1) mx = fmaxf(mx, __shfl_xor(mx, off));
        float sm = 0.f;
        #pragma unroll
        for (int jj = 0; jj < 4; jj++)
            if (vld[jj]) sm += expf(l[jj] - mx);
        #pragma unroll
        for (int off = 1; off < 32; off <<= 1) sm += __shfl_xor(sm, off);
        if (tj == 0) { pmax[b * NSTEP + s] = mx; psum[b * NSTEP + s] = sm; }
        int tgt = enums[s + 1];
        if (tgt >= v0 && tgt < v0 + VTILE) {
            int c = tgt - v0;
            if ((c & 31) == tj) pick[s] = l[c >> 5];
        }
    }
}

// ---- K5: combine partial logsumexps, pick target logprobs, sum ----
__global__ void k_final(const float* __restrict__ pmax, const float* __restrict__ psum,
                        const float* __restrict__ pick, float* __restrict__ out) {
    __shared__ float red[NSTEP];
    int t = threadIdx.x;     // 128 threads, one per decoder step
    float M = -1e30f;
    for (int b = 0; b < NBV; b++) M = fmaxf(M, pmax[b * NSTEP + t]);
    float S = 0.f;
    for (int b = 0; b < NBV; b++) S += psum[b * NSTEP + t] * expf(pmax[b * NSTEP + t] - M);
    red[t] = pick[t] - (M + logf(S));
    __syncthreads();
    for (int off = 64; off > 0; off >>= 1) {
        if (t < off) red[t] += red[t + off];
        __syncthreads();
    }
    if (t == 0) out[0] = red[0];
}

extern "C" void kernel_launch(void* const* d_in, const int* in_sizes, int n_in,
                              void* d_out, int out_size, void* d_ws, size_t ws_size,
                              hipStream_t stream) {
    const int*   fnums = (const int*)  d_in[0];
    const int*   enums = (const int*)  d_in[1];
    const float* emb_f = (const float*)d_in[2];
    const float* Wih_e = (const float*)d_in[3];
    const float* Whh_e = (const float*)d_in[4];
    const float* b_e   = (const float*)d_in[5];
    const float* h0_e  = (const float*)d_in[6];
    const float* emb_d = (const float*)d_in[7];
    const float* Wih_d = (const float*)d_in[8];
    const float* Whh_d = (const float*)d_in[9];
    const float* b_d   = (const float*)d_in[10];
    const float* h0_d  = (const float*)d_in[11];
    const float* Wm    = (const float*)d_in[12];
    const float* bm    = (const float*)d_in[13];
    const float* Wo    = (const float*)d_in[14];
    const float* bo    = (const float*)d_in[15];

    float* ws = (float*)d_ws;
    float* pre_e = ws;                       // 65536
    float* pre_d = ws + 65536;               // 65536
    float* fencs = ws + 131072;              // 65536
    float* h2s   = ws + 196608;              // 65536
    float* pmax  = ws + 262144;              // 50048
    float* psum  = ws + 312192;              // 50048
    float* pick  = ws + 362240;              // 128
    float* qsc   = ws + 362368;              // 1024
    int8_t* q8   = (int8_t*)(ws + 363392);   // 512 KB scan weights
    float* wosc  = ws + 494464;              // 50048
    int8_t* mq   = (int8_t*)(ws + 544512);   // 64 KB
    int8_t* woq  = (int8_t*)(ws + 560896);   // 25.6 MB

    k_quant<<<dim3(1024), dim3(64), 0, stream>>>(Whh_e, Whh_d, q8, qsc);
    k_quant_wo<<<dim3((EVOC + 3) / 4), dim3(256), 0, stream>>>(Wo, woq, wosc);
    k_pre<<<dim3(256), dim3(256), 0, stream>>>(fnums, enums, emb_f, emb_d,
                                               Wih_e, Wih_d, b_e, b_d, pre_e, pre_d);
    k_scan<<<dim3(2), dim3(1024), 0, stream>>>(q8, qsc, pre_e, pre_d, h0_e, h0_d, fencs, h2s);
    k_att<<<dim3(NSTEP), dim3(256), 0, stream>>>(fencs, h2s, Wm, bm, mq);
    k_logits<<<dim3(NBV), dim3(512), 0, stream>>>(mq, woq, wosc, bo, enums, pmax, psum, pick);
    k_final<<<dim3(1), dim3(NSTEP), 0, stream>>>(pmax, psum, pick, (float*)d_out);
}

// Round 7
// 450.735 us; speedup vs baseline: 6.5093x; 1.0018x over previous
//
#include <hip/hip_runtime.h>
#include <stdint.h>

#define D      512
#define NSTEP  128          // SRC steps == decoder steps (TGT-1)
#define EVOC   50000
#define VTILE  128
#define NBV    ((EVOC + VTILE - 1) / VTILE)   // 391
#define LDA_W  36           // A LDS row stride in u32 words (144 B, 16B-aligned)
#define LDB_W  129          // B LDS kw-row stride in u32 words (128 cols + 1 pad)

// ---- int8 dot4 (v_dot4_i32_i8) ----
__device__ inline int sdot4(int a, int b, int c) {
#if __has_builtin(__builtin_amdgcn_sdot4)
    return __builtin_amdgcn_sdot4(a, b, c, false);
#else
    int r = c;
    r += (int)(int8_t)(a)       * (int)(int8_t)(b);
    r += (int)(int8_t)(a >> 8)  * (int)(int8_t)(b >> 8);
    r += (int)(int8_t)(a >> 16) * (int)(int8_t)(b >> 16);
    r += (int)(int8_t)(a >> 24) * (int)(int8_t)(b >> 24);
    return r;
#endif
}

__device__ inline uint32_t pack4(float a, float b, float c, float d, float inv) {
    return  ((uint32_t)(uint8_t)(int8_t)__float2int_rn(a * inv)) |
            ((uint32_t)(uint8_t)(int8_t)__float2int_rn(b * inv) << 8) |
            ((uint32_t)(uint8_t)(int8_t)__float2int_rn(c * inv) << 16) |
            ((uint32_t)(uint8_t)(int8_t)__float2int_rn(d * inv) << 24);
}

// ---- K0: per-row symmetric int8 quantization of Whh_e / Whh_d ----
__global__ __launch_bounds__(64) void k_quant(
        const float* __restrict__ We, const float* __restrict__ Wd,
        int8_t* __restrict__ q8, float* __restrict__ qsc) {
    int bid = blockIdx.x;                 // 0..1023
    int which = bid >> 9, row = bid & 511;
    const float* W = which ? Wd : We;
    int lane = threadIdx.x;
    const float* src = W + (size_t)row * D + lane * 8;
    float4 v0 = ((const float4*)src)[0];
    float4 v1 = ((const float4*)src)[1];
    float m = fmaxf(fmaxf(fmaxf(fabsf(v0.x), fabsf(v0.y)), fmaxf(fabsf(v0.z), fabsf(v0.w))),
                    fmaxf(fmaxf(fabsf(v1.x), fabsf(v1.y)), fmaxf(fabsf(v1.z), fabsf(v1.w))));
    for (int off = 32; off; off >>= 1) m = fmaxf(m, __shfl_xor(m, off));
    float inv = (m > 0.f) ? 127.f / m : 0.f;
    uint32_t lo = pack4(v0.x, v0.y, v0.z, v0.w, inv);
    uint32_t hi = pack4(v1.x, v1.y, v1.z, v1.w, inv);
    uint2* dst = (uint2*)(q8 + (size_t)which * D * D + (size_t)row * D);
    dst[lane] = make_uint2(lo, hi);
    if (lane == 0) qsc[which * D + row] = m / 127.f;
}

// ---- K0b: per-row int8 quantization of Wo (50000 x 512), 4 rows/block ----
__global__ __launch_bounds__(256) void k_quant_wo(
        const float* __restrict__ Wo, int8_t* __restrict__ woq,
        float* __restrict__ wosc) {
    int row = blockIdx.x * 4 + (threadIdx.x >> 6);
    if (row >= EVOC) return;
    int lane = threadIdx.x & 63;
    const float4* src = (const float4*)(Wo + (size_t)row * D);
    float4 v0 = src[lane];
    float4 v1 = src[lane + 64];
    float m = fmaxf(fmaxf(fmaxf(fabsf(v0.x), fabsf(v0.y)), fmaxf(fabsf(v0.z), fabsf(v0.w))),
                    fmaxf(fmaxf(fabsf(v1.x), fabsf(v1.y)), fmaxf(fabsf(v1.z), fabsf(v1.w))));
    for (int off = 32; off; off >>= 1) m = fmaxf(m, __shfl_xor(m, off));
    float inv = (m > 0.f) ? 127.f / m : 0.f;
    uint32_t* dst = (uint32_t*)(woq + (size_t)row * D);
    dst[lane]      = pack4(v0.x, v0.y, v0.z, v0.w, inv);
    dst[lane + 64] = pack4(v1.x, v1.y, v1.z, v1.w, inv);
    if (lane == 0) wosc[row] = m / 127.f;
}

// ---- K1: pre[s][o] = emb[idx[s]] . Wih[o,:] + b[o]   (both enc & dec) ----
__global__ __launch_bounds__(256) void k_pre(
        const int* __restrict__ fnums, const int* __restrict__ enums,
        const float* __restrict__ emb_f, const float* __restrict__ emb_d,
        const float* __restrict__ Wih_e, const float* __restrict__ Wih_d,
        const float* __restrict__ b_e, const float* __restrict__ b_d,
        float* __restrict__ pre_e, float* __restrict__ pre_d) {
    __shared__ float xl[D];
    int bb = blockIdx.x;            // 0..255 : 128 enc + 128 dec
    int kind = bb >> 7, s = bb & 127;
    const float* emb = kind ? emb_d : emb_f;
    int idx          = kind ? enums[s] : fnums[s];
    const float* W   = kind ? Wih_d : Wih_e;
    const float* b   = kind ? b_d : b_e;
    float* pre       = kind ? pre_d : pre_e;
    int t = threadIdx.x;
    xl[t]       = emb[(size_t)idx * D + t];
    xl[t + 256] = emb[(size_t)idx * D + t + 256];
    __syncthreads();
    for (int rep = 0; rep < 2; rep++) {
        int o = t + rep * 256;
        float acc = b[o];
        const float4* Wr = (const float4*)(W + (size_t)o * D);
        #pragma unroll 8
        for (int k4 = 0; k4 < D / 4; k4++) {
            float4 w = Wr[k4];
            acc += w.x * xl[4*k4] + w.y * xl[4*k4+1] + w.z * xl[4*k4+2] + w.w * xl[4*k4+3];
        }
        pre[(size_t)s * D + o] = acc;
    }
}

// ---- K2: the two sequential scans, int8 x dot4. ----
// Weights live in 16 NAMED uint4 registers (no array -> no alloca -> cannot be
// demoted to scratch). Two prior attribute-only attempts left the w[64] alloca
// in scratch (VGPR_Count=44, 183us, ~3430cyc/step of L2 scratch re-reads).
// __launch_bounds__(1024,4): 4 waves/EU = exactly one 16-wave block -> 128-VGPR
// budget; named regs need ~110.
__global__ __launch_bounds__(1024, 4) void k_scan(
        const int8_t* __restrict__ q8, const float* __restrict__ qsc,
        const float* __restrict__ pre_e, const float* __restrict__ pre_d,
        const float* __restrict__ h0_e, const float* __restrict__ h0_d,
        float* __restrict__ fencs, float* __restrict__ h2s) {
    __shared__ int8_t hq[2][D];
    int t = threadIdx.x;
    int r = t >> 1, hf = t & 1;
    int which = blockIdx.x;
    const int8_t* w8 = q8 + (size_t)which * D * D;
    const float*  pre = which ? pre_d : pre_e;
    const float*  h0  = which ? h0_d : h0_e;
    float*        hs  = which ? h2s : fencs;
    float sw = qsc[which * D + r] * (1.f / 127.f);

    // 256 int8 weights in 16 named uint4 registers (64 VGPRs)
    const uint4* wr = (const uint4*)(w8 + (size_t)r * D + hf * 256);
    uint4 w0  = wr[0],  w1  = wr[1],  w2  = wr[2],  w3  = wr[3];
    uint4 w4  = wr[4],  w5  = wr[5],  w6  = wr[6],  w7  = wr[7];
    uint4 w8v = wr[8],  w9  = wr[9],  w10 = wr[10], w11 = wr[11];
    uint4 w12 = wr[12], w13 = wr[13], w14 = wr[14], w15 = wr[15];

    if (hf == 0) {
        float h0v = fminf(fmaxf(h0[r], -0.999f), 0.999f);
        hq[0][r] = (int8_t)__float2int_rn(h0v * 127.f);
    }
    __syncthreads();

    int p = 0;
    for (int step = 0; step < NSTEP; step++) {
        float prev = pre[(size_t)step * D + r];    // same addr for lane pair (broadcast)
        const uint4* hv = (const uint4*)(&hq[p][hf * 256]);
        int a0 = 0, a1 = 0, a2 = 0, a3 = 0;
        #define DOT_STEP(i, wv) { uint4 hx = hv[i];            \
            a0 = sdot4((int)(wv).x, (int)hx.x, a0);            \
            a1 = sdot4((int)(wv).y, (int)hx.y, a1);            \
            a2 = sdot4((int)(wv).z, (int)hx.z, a2);            \
            a3 = sdot4((int)(wv).w, (int)hx.w, a3); }
        DOT_STEP(0,  w0)  DOT_STEP(1,  w1)  DOT_STEP(2,  w2)  DOT_STEP(3,  w3)
        DOT_STEP(4,  w4)  DOT_STEP(5,  w5)  DOT_STEP(6,  w6)  DOT_STEP(7,  w7)
        DOT_STEP(8,  w8v) DOT_STEP(9,  w9)  DOT_STEP(10, w10) DOT_STEP(11, w11)
        DOT_STEP(12, w12) DOT_STEP(13, w13) DOT_STEP(14, w14) DOT_STEP(15, w15)
        #undef DOT_STEP
        int acc = (a0 + a1) + (a2 + a3);
        acc += __shfl_xor(acc, 1);                 // combine the two half-rows
        if (hf == 0) {
            float h2 = tanhf(prev + (float)acc * sw);
            hs[(size_t)step * D + r] = h2;
            hq[p ^ 1][r] = (int8_t)__float2int_rn(h2 * 127.f);
        }
        p ^= 1;
        __syncthreads();
    }
}

// ---- K3: per decoder step: attention + m = tanh([c,h2] @ Wm^T + bm) -> int8 ----
__global__ __launch_bounds__(256) void k_att(
        const float* __restrict__ fencs, const float* __restrict__ h2s,
        const float* __restrict__ Wm, const float* __restrict__ bm,
        int8_t* __restrict__ mq) {
    __shared__ float h2l[D], cl[D], sc[NSTEP], red[64];
    int s = blockIdx.x, t = threadIdx.x;
    h2l[t]       = h2s[(size_t)s * D + t];
    h2l[t + 256] = h2s[(size_t)s * D + t + 256];
    __syncthreads();

    if (t < NSTEP) {                    // scores[j] = fencs[j] . h2
        float acc = 0.f;
        const float4* fr = (const float4*)(fencs + (size_t)t * D);
        const float4* hr = (const float4*)h2l;
        #pragma unroll 8
        for (int k4 = 0; k4 < D / 4; k4++) {
            float4 f = fr[k4], hh = hr[k4];
            acc += f.x*hh.x + f.y*hh.y + f.z*hh.z + f.w*hh.w;
        }
        sc[t] = acc;
    }
    __syncthreads();
    if (t < 64) {
        float m = fmaxf(sc[t], sc[t + 64]);
        for (int off = 32; off; off >>= 1) m = fmaxf(m, __shfl_xor(m, off));
        if (t == 0) red[0] = m;
    }
    __syncthreads();
    float mx = red[0];
    __syncthreads();
    if (t < NSTEP) sc[t] = expf(sc[t] - mx);
    __syncthreads();
    if (t < 64) {
        float v = sc[t] + sc[t + 64];
        for (int off = 32; off; off >>= 1) v += __shfl_xor(v, off);
        if (t == 0) red[0] = v;
    }
    __syncthreads();
    float inv = 1.0f / red[0];

    for (int rep = 0; rep < 2; rep++) {         // c[k] = sum_j alpha[j]*fencs[j][k]
        int k = t + rep * 256;
        float acc = 0.f;
        for (int j = 0; j < NSTEP; j++) acc += sc[j] * fencs[(size_t)j * D + k];
        cl[k] = acc * inv;
    }
    __syncthreads();

    for (int rep = 0; rep < 2; rep++) {         // m[o] = tanh(Wm[o,:512].c + Wm[o,512:].h2 + bm)
        int o = t + rep * 256;
        float acc = bm[o];
        const float4* wr = (const float4*)(Wm + (size_t)o * 2 * D);
        const float4* cr = (const float4*)cl;
        const float4* hr = (const float4*)h2l;
        #pragma unroll 4
        for (int k4 = 0; k4 < D / 4; k4++) {
            float4 w = wr[k4], c = cr[k4];
            acc += w.x*c.x + w.y*c.y + w.z*c.z + w.w*c.w;
        }
        #pragma unroll 4
        for (int k4 = 0; k4 < D / 4; k4++) {
            float4 w = wr[D/4 + k4], hh = hr[k4];
            acc += w.x*hh.x + w.y*hh.y + w.z*hh.z + w.w*hh.w;
        }
        float mval = tanhf(acc);
        mq[(size_t)s * D + o] = (int8_t)__float2int_rn(mval * 127.f);
    }
}

// ---- K4: int8 logits GEMM (128 steps x 128 vocab, K=512) + fused row max/sumexp ----
// A LDS [row][36 u32-words] (16B-aligned rows; b128 reads broadcast, 2-way=free)
// B LDS [kw][129 cols] (scalar b32 reads, lane stride 1 -> 32 banks, conflict-free)
__global__ __launch_bounds__(512) void k_logits(
        const int8_t* __restrict__ mq, const int8_t* __restrict__ woq,
        const float* __restrict__ wosc, const float* __restrict__ bo,
        const int* __restrict__ enums,
        float* __restrict__ pmax, float* __restrict__ psum, float* __restrict__ pick) {
    __shared__ uint32_t a_s[128 * LDA_W];   // 18.4 KB
    __shared__ uint32_t b_s[32 * LDB_W];    // 16.5 KB
    int b = blockIdx.x, t = threadIdx.x;
    int v0 = b * VTILE;
    int ti = t >> 5, tj = t & 31;           // out: rows ti*8+i, cols tj+32*jj
    int lrow = t >> 3, lq = t & 7;          // staging: 64 rows/rep, 8 16B-quads/row
    int acc[8][4] = {};

    for (int kc = 0; kc < 4; kc++) {        // K chunks of 128 int8 (32 words)
        #pragma unroll
        for (int rep = 0; rep < 2; rep++) {
            int row = lrow + rep * 64;
            uint4 av = *(const uint4*)(mq + (size_t)row * D + kc * 128 + lq * 16);
            *(uint4*)&a_s[row * LDA_W + lq * 4] = av;
            int v = v0 + row;
            uint4 bv = (v < EVOC)
                ? *(const uint4*)(woq + (size_t)v * D + kc * 128 + lq * 16)
                : make_uint4(0u, 0u, 0u, 0u);
            b_s[(lq*4+0) * LDB_W + row] = bv.x;
            b_s[(lq*4+1) * LDB_W + row] = bv.y;
            b_s[(lq*4+2) * LDB_W + row] = bv.z;
            b_s[(lq*4+3) * LDB_W + row] = bv.w;
        }
        __syncthreads();
        #pragma unroll
        for (int q = 0; q < 8; q++) {
            uint4 aw[8];
            #pragma unroll
            for (int i = 0; i < 8; i++)
                aw[i] = *(const uint4*)&a_s[(ti*8 + i) * LDA_W + q*4];
            #pragma unroll
            for (int k4 = 0; k4 < 4; k4++) {
                uint32_t bw[4];
                #pragma unroll
                for (int jj = 0; jj < 4; jj++)
                    bw[jj] = b_s[(q*4 + k4) * LDB_W + tj + 32*jj];
                #pragma unroll
                for (int i = 0; i < 8; i++) {
                    uint32_t a = (k4 == 0) ? aw[i].x : (k4 == 1) ? aw[i].y
                               : (k4 == 2) ? aw[i].z : aw[i].w;
                    #pragma unroll
                    for (int jj = 0; jj < 4; jj++)
                        acc[i][jj] = sdot4((int)a, (int)bw[jj], acc[i][jj]);
                }
            }
        }
        __syncthreads();
    }

    // epilogue: per-column scale + bias, then per-row max/sumexp across 32 lanes
    float sw4[4], bo4[4];
    int vld[4];
    #pragma unroll
    for (int jj = 0; jj < 4; jj++) {
        int v = v0 + tj + 32*jj;
        vld[jj] = (v < EVOC);
        sw4[jj] = vld[jj] ? wosc[v] * (1.f/127.f) : 0.f;
        bo4[jj] = vld[jj] ? bo[v] : 0.f;
    }
    #pragma unroll
    for (int i = 0; i < 8; i++) {
        int s = ti * 8 + i;
        float l[4];
        float mx = -1e30f;
        #pragma unroll
        for (int jj = 0; jj < 4; jj++) {
            l[jj] = vld[jj] ? (float)acc[i][jj] * sw4[jj] + bo4[jj] : -1e30f;
            mx = fmaxf(mx, l[jj]);
        }
        #pragma unroll
        for (int off = 1; off < 32; off <<= 1) mx = fmaxf(mx, __shfl_xor(mx, off));
        float sm = 0.f;
        #pragma unroll
        for (int jj = 0; jj < 4; jj++)
            if (vld[jj]) sm += expf(l[jj] - mx);
        #pragma unroll
        for (int off = 1; off < 32; off <<= 1) sm += __shfl_xor(sm, off);
        if (tj == 0) { pmax[b * NSTEP + s] = mx; psum[b * NSTEP + s] = sm; }
        int tgt = enums[s + 1];
        if (tgt >= v0 && tgt < v0 + VTILE) {
            int c = tgt - v0;
            if ((c & 31) == tj) pick[s] = l[c >> 5];
        }
    }
}

// ---- K5: combine partial logsumexps, pick target logprobs, sum ----
__global__ void k_final(const float* __restrict__ pmax, const float* __restrict__ psum,
                        const float* __restrict__ pick, float* __restrict__ out) {
    __shared__ float red[NSTEP];
    int t = threadIdx.x;     // 128 threads, one per decoder step
    float M = -1e30f;
    for (int b = 0; b < NBV; b++) M = fmaxf(M, pmax[b * NSTEP + t]);
    float S = 0.f;
    for (int b = 0; b < NBV; b++) S += psum[b * NSTEP + t] * expf(pmax[b * NSTEP + t] - M);
    red[t] = pick[t] - (M + logf(S));
    __syncthreads();
    for (int off = 64; off > 0; off >>= 1) {
        if (t < off) red[t] += red[t + off];
        __syncthreads();
    }
    if (t == 0) out[0] = red[0];
}

extern "C" void kernel_launch(void* const* d_in, const int* in_sizes, int n_in,
                              void* d_out, int out_size, void* d_ws, size_t ws_size,
                              hipStream_t stream) {
    const int*   fnums = (const int*)  d_in[0];
    const int*   enums = (const int*)  d_in[1];
    const float* emb_f = (const float*)d_in[2];
    const float* Wih_e = (const float*)d_in[3];
    const float* Whh_e = (const float*)d_in[4];
    const float* b_e   = (const float*)d_in[5];
    const float* h0_e  = (const float*)d_in[6];
    const float* emb_d = (const float*)d_in[7];
    const float* Wih_d = (const float*)d_in[8];
    const float* Whh_d = (const float*)d_in[9];
    const float* b_d   = (const float*)d_in[10];
    const float* h0_d  = (const float*)d_in[11];
    const float* Wm    = (const float*)d_in[12];
    const float* bm    = (const float*)d_in[13];
    const float* Wo    = (const float*)d_in[14];
    const float* bo    = (const float*)d_in[15];

    float* ws = (float*)d_ws;
    float* pre_e = ws;                       // 65536
    float* pre_d = ws + 65536;               // 65536
    float* fencs = ws + 131072;              // 65536
    float* h2s   = ws + 196608;              // 65536
    float* pmax  = ws + 262144;              // 50048
    float* psum  = ws + 312192;              // 50048
    float* pick  = ws + 362240;              // 128
    float* qsc   = ws + 362368;              // 1024
    int8_t* q8   = (int8_t*)(ws + 363392);   // 512 KB scan weights
    float* wosc  = ws + 494464;              // 50048
    int8_t* mq   = (int8_t*)(ws + 544512);   // 64 KB
    int8_t* woq  = (int8_t*)(ws + 560896);   // 25.6 MB

    k_quant<<<dim3(1024), dim3(64), 0, stream>>>(Whh_e, Whh_d, q8, qsc);
    k_quant_wo<<<dim3((EVOC + 3) / 4), dim3(256), 0, stream>>>(Wo, woq, wosc);
    k_pre<<<dim3(256), dim3(256), 0, stream>>>(fnums, enums, emb_f, emb_d,
                                               Wih_e, Wih_d, b_e, b_d, pre_e, pre_d);
    k_scan<<<dim3(2), dim3(1024), 0, stream>>>(q8, qsc, pre_e, pre_d, h0_e, h0_d, fencs, h2s);
    k_att<<<dim3(NSTEP), dim3(256), 0, stream>>>(fencs, h2s, Wm, bm, mq);
    k_logits<<<dim3(NBV), dim3(512), 0, stream>>>(mq, woq, wosc, bo, enums, pmax, psum, pick);
    k_final<<<dim3(1), dim3(NSTEP), 0, stream>>>(pmax, psum, pick, (float*)d_out);
}